// Round 2
// baseline (361.206 us; speedup 1.0000x reference)
//
#include <hip/hip_runtime.h>
#include <math.h>

// Problem constants
constexpr int Bn = 2, Ln = 128, Dn = 256, Hn = 256;

// log(expm1(0.01))
#define LR_SHIFT (-4.6001660040607144f)

// Workspace offsets (floats)
constexpr int OFF_Q      = 0;        // [B,L,D]
constexpr int OFF_K      = 65536;    // [B,L,D]
constexpr int OFF_V      = 131072;   // [B,L,D]  (dead after fstage<1>; reused for P1/P2)
constexpr int OFF_X2     = 196608;   // [B,L,H]
constexpr int OFF_GZ1    = 262144;   // [B,L,H]  (holds Z1 between fstage<0> and fstage<2>)
constexpr int OFF_GZ2    = 327680;   // [B,L,D]
constexpr int OFF_XQ     = 393216;   // [B,L,H]
constexpr int OFF_KT     = 458752;   // [B,256,128]  K transposed (feature-major)
constexpr int OFF_A      = 524288;   // [B,L,L]  A = Dm@M (lower-tri)
constexpr int OFF_W1T    = 557056;   // [B,D,H]  W1 transposed
constexpr int OFF_W2T    = 688128;   // [B,H,D]  W2 transposed
constexpr int OFF_MW1T   = 819200;   // [B,D,H]
constexpr int OFF_MW2T   = 950272;   // [B,H,D]
constexpr int OFF_LR     = 1081344;  // [B,L]
constexpr int OFF_PM     = 1081600;  // [B,L] prefix sum of log_mom (inclusive)
constexpr int OFF_PD     = 1081856;  // [B,L] prefix sum of log_wd
constexpr int OFF_MOMCUM = 1082112;  // [B,L]
constexpr int OFF_WDCUM  = 1082368;  // [B,L]
constexpr int OFF_C      = 1082624;  // [B,L]  c = Dm @ mom_cum
constexpr int OFF_LOGM   = 1082880;  // [B,L]
constexpr int OFF_LOGWD  = 1083136;  // [B,L]
constexpr int OFF_X2T    = 1083392;  // [B,256,128]  X2 transposed
// P1/P2 alias the dead V buffer ([B,128,128] each = 32768 floats; V = 65536)
constexpr int OFF_P1     = OFF_V;
constexpr int OFF_P2     = OFF_V + 32768;
// total 1148928 floats ~= 4.6 MB (unchanged)

// Output offsets (floats), tuple order
constexpr int OUT_ZQ2  = 0;       // [B,L,D]
constexpr int OUT_W1P  = 65536;   // [B,H,D]
constexpr int OUT_B1P  = 196608;  // [B,H]
constexpr int OUT_W2P  = 197120;  // [B,D,H]
constexpr int OUT_B2P  = 328192;  // [B,D]
constexpr int OUT_MGW1 = 328704;  // [B,H,D]
constexpr int OUT_MGB1 = 459776;  // [B,H]
constexpr int OUT_MGW2 = 460288;  // [B,D,H]
constexpr int OUT_MGB2 = 591360;  // [B,D]

__device__ __forceinline__ float softplus_f(float z) {
    return fmaxf(z, 0.0f) + log1pf(expf(-fabsf(z)));
}

__device__ __forceinline__ float4 fma4(float s, const float4 w, float4 a) {
    a.x += s * w.x; a.y += s * w.y; a.z += s * w.z; a.w += s * w.w; return a;
}

__device__ __forceinline__ float silu_f(float z) {
    return z / (1.0f + expf(-z));
}

// ---------------------------------------------------------------------------
// k0: transpose W1, W2, mW1, mW2 (each [256,256] per batch) into workspace
// ---------------------------------------------------------------------------
__global__ __launch_bounds__(256) void transpose_kernel(
    const float* __restrict__ W1, const float* __restrict__ W2,
    const float* __restrict__ mW1, const float* __restrict__ mW2,
    float* __restrict__ ws) {
    int z = blockIdx.z; int mat = z >> 1; int b = z & 1;
    const float* src; float* dst;
    if (mat == 0)      { src = W1  + b * 65536; dst = ws + OFF_W1T  + b * 65536; }
    else if (mat == 1) { src = W2  + b * 65536; dst = ws + OFF_W2T  + b * 65536; }
    else if (mat == 2) { src = mW1 + b * 65536; dst = ws + OFF_MW1T + b * 65536; }
    else               { src = mW2 + b * 65536; dst = ws + OFF_MW2T + b * 65536; }
    __shared__ float tile[32][33];
    int tx = threadIdx.x & 31, ty = threadIdx.x >> 5;
    int r0 = blockIdx.y * 32, c0 = blockIdx.x * 32;
    for (int i = 0; i < 32; i += 8)
        tile[ty + i][tx] = src[(r0 + ty + i) * 256 + (c0 + tx)];
    __syncthreads();
    for (int i = 0; i < 32; i += 8)
        dst[(c0 + ty + i) * 256 + (r0 + tx)] = tile[tx][ty + i];
}

// ---------------------------------------------------------------------------
// k1: QKV projection. Tile = 16 tok x 128 cols, 256 threads (4 waves).
// Thread = 2 tokens x 1 col-quad (2 float4 accs = 8 indep FMA chains).
// Weight loads hand-batched 8-deep into registers -> >=8 (16 w/ unroll2)
// outstanding L2 loads per wave. grid (2 ctiles, 16 ttiles, 3 mats).
// ---------------------------------------------------------------------------
__global__ __launch_bounds__(256) void qkv_kernel(
    const float* __restrict__ x,
    const float* __restrict__ Wq, const float* __restrict__ bq,
    const float* __restrict__ Wk, const float* __restrict__ bk,
    const float* __restrict__ Wv, const float* __restrict__ bv,
    float* __restrict__ ws) {
    int mat = blockIdx.z;
    const float* W    = (mat == 0) ? Wq : (mat == 1) ? Wk : Wv;
    const float* bias = (mat == 0) ? bq : (mat == 1) ? bk : bv;
    int outoff = (mat == 0) ? OFF_Q : (mat == 1) ? OFF_K : OFF_V;
    int bl0 = blockIdx.y * 16;
    int c0  = blockIdx.x * 128;
    int t = threadIdx.x;
    __shared__ float xs[16][260];
    for (int i = t; i < 1024; i += 256) {
        int tok = i >> 6, kq = i & 63;
        *(float4*)&xs[tok][kq * 4] = *(const float4*)(x + (bl0 + tok) * 256 + kq * 4);
    }
    __syncthreads();
    int tg = t >> 5, q = t & 31;
    int tok0 = 2 * tg, tok1 = tok0 + 1;
    int c = c0 + 4 * q;
    const float* Wp = W + c;
    float4 a0 = {0, 0, 0, 0}, a1 = {0, 0, 0, 0};
#pragma unroll 2
    for (int k0 = 0; k0 < 256; k0 += 8) {
        float4 wb[8];
#pragma unroll
        for (int kk = 0; kk < 8; ++kk)
            wb[kk] = *(const float4*)(Wp + (k0 + kk) * 256);
#pragma unroll
        for (int kk = 0; kk < 8; ++kk) {
            a0 = fma4(xs[tok0][k0 + kk], wb[kk], a0);
            a1 = fma4(xs[tok1][k0 + kk], wb[kk], a1);
        }
    }
    float4 bb = *(const float4*)(bias + c);
    a0.x += bb.x; a0.y += bb.y; a0.z += bb.z; a0.w += bb.w;
    a1.x += bb.x; a1.y += bb.y; a1.z += bb.z; a1.w += bb.w;
    *(float4*)(ws + outoff + (bl0 + tok0) * 256 + c) = a0;
    *(float4*)(ws + outoff + (bl0 + tok1) * 256 + c) = a1;
}

// ---------------------------------------------------------------------------
// k1b: scalar projections (lr / log_mom / log_wd). One wave per token.
// ---------------------------------------------------------------------------
__global__ __launch_bounds__(256) void scalproj_kernel(
    const float* __restrict__ x,
    const float* __restrict__ Wlr, const float* __restrict__ blr,
    const float* __restrict__ Wm, const float* __restrict__ bm,
    const float* __restrict__ Wd, const float* __restrict__ bd,
    float* __restrict__ ws) {
    int t = threadIdx.x;
    int ln = t & 63, wv = t >> 6;
    int bl = blockIdx.x * 4 + wv;   // global token
    float4 xv = *(const float4*)(x + bl * 256 + ln * 4);
    float4 wl = *(const float4*)(Wlr + ln * 4);
    float4 wm = *(const float4*)(Wm + ln * 4);
    float4 wd = *(const float4*)(Wd + ln * 4);
    float s1 = xv.x * wl.x + xv.y * wl.y + xv.z * wl.z + xv.w * wl.w;
    float s2 = xv.x * wm.x + xv.y * wm.y + xv.z * wm.z + xv.w * wm.w;
    float s3 = xv.x * wd.x + xv.y * wd.y + xv.z * wd.z + xv.w * wd.w;
#pragma unroll
    for (int off = 32; off > 0; off >>= 1) {
        s1 += __shfl_xor(s1, off);
        s2 += __shfl_xor(s2, off);
        s3 += __shfl_xor(s3, off);
    }
    if (ln == 0) {
        ws[OFF_LR + bl]    = softplus_f(s1 + blr[0] + LR_SHIFT);
        ws[OFF_LOGM + bl]  = -softplus_f(-(s2 + bm[0]));
        ws[OFF_LOGWD + bl] = -softplus_f(s3 + bd[0]);
    }
}

// ---------------------------------------------------------------------------
// k2: per-batch prefix scans -> Pm, Pd, mom_cum, wd_cum, c
// ---------------------------------------------------------------------------
__global__ __launch_bounds__(128) void scan_kernel(float* __restrict__ ws) {
    int b = blockIdx.x; int t = threadIdx.x;
    __shared__ float sm[128], sd[128], se[128];
    sm[t] = ws[OFF_LOGM + b * Ln + t];
    sd[t] = ws[OFF_LOGWD + b * Ln + t];
    __syncthreads();
    for (int off = 1; off < 128; off <<= 1) {
        float am = (t >= off) ? sm[t - off] : 0.0f;
        float ad = (t >= off) ? sd[t - off] : 0.0f;
        __syncthreads();
        sm[t] += am; sd[t] += ad;
        __syncthreads();
    }
    float pm = sm[t], pd = sd[t];
    ws[OFF_PM + b * Ln + t] = pm;
    ws[OFF_PD + b * Ln + t] = pd;
    ws[OFF_MOMCUM + b * Ln + t] = expf(pm);
    ws[OFF_WDCUM + b * Ln + t]  = expf(pd);
    se[t] = expf(pm - pd);
    __syncthreads();
    for (int off = 1; off < 128; off <<= 1) {
        float a = (t >= off) ? se[t - off] : 0.0f;
        __syncthreads();
        se[t] += a;
        __syncthreads();
    }
    ws[OFF_C + b * Ln + t] = expf(pd) * se[t];
}

// ---------------------------------------------------------------------------
// k3: A = Dm @ M  (lower-tri, per batch)
// ---------------------------------------------------------------------------
__global__ __launch_bounds__(128) void a_kernel(float* __restrict__ ws) {
    int bl = blockIdx.x; int b = bl >> 7; int l = bl & 127;
    int m1 = threadIdx.x;
    const float* Pm = ws + OFF_PM + b * Ln;
    const float* Pd = ws + OFF_PD + b * Ln;
    float a = 0.0f;
    if (m1 <= l) {
        float pdl = Pd[l], pmm1 = Pm[m1];
        float s = 0.0f;
        for (int m = m1; m <= l; ++m)
            s += expf((pdl - Pd[m]) + (Pm[m] - pmm1));
        a = s;
    }
    ws[OFF_A + bl * Ln + m1] = a;
}

// ---------------------------------------------------------------------------
// k4: forward MLP + grads, same high-ILP tile as qkv.
// MODE 0: Z1 = K @ W1t + b1 -> park Z1 in GZ1, X2 = silu(Z1)
// MODE 1: gZ2 = X2 @ W2t + b2 - V
// MODE 2: gX2 = gZ2 @ W2(native); gZ1 = gX2 * silu'(Z1)  (in-place on GZ1)
// grid (2 ctiles, 16 ttiles). Tokens global; per-batch weights.
// ---------------------------------------------------------------------------
template <int MODE>
__global__ __launch_bounds__(256) void fstage_kernel(
    const float* __restrict__ W2nat, const float* __restrict__ b1,
    const float* __restrict__ b2, float* __restrict__ ws) {
    int bl0 = blockIdx.y * 16;
    int b = bl0 >> 7;
    int c0 = blockIdx.x * 128;
    const float* in; const float* W;
    if (MODE == 0)      { in = ws + OFF_K;   W = ws + OFF_W1T + b * 65536; }
    else if (MODE == 1) { in = ws + OFF_X2;  W = ws + OFF_W2T + b * 65536; }
    else                { in = ws + OFF_GZ2; W = W2nat + b * 65536; }
    int t = threadIdx.x;
    __shared__ float xs[16][260];
    for (int i = t; i < 1024; i += 256) {
        int tok = i >> 6, kq = i & 63;
        *(float4*)&xs[tok][kq * 4] = *(const float4*)(in + (bl0 + tok) * 256 + kq * 4);
    }
    __syncthreads();
    int tg = t >> 5, q = t & 31;
    int tok0 = 2 * tg, tok1 = tok0 + 1;
    int c = c0 + 4 * q;
    const float* Wp = W + c;
    float4 a0 = {0, 0, 0, 0}, a1 = {0, 0, 0, 0};
#pragma unroll 2
    for (int k0 = 0; k0 < 256; k0 += 8) {
        float4 wb[8];
#pragma unroll
        for (int kk = 0; kk < 8; ++kk)
            wb[kk] = *(const float4*)(Wp + (k0 + kk) * 256);
#pragma unroll
        for (int kk = 0; kk < 8; ++kk) {
            a0 = fma4(xs[tok0][k0 + kk], wb[kk], a0);
            a1 = fma4(xs[tok1][k0 + kk], wb[kk], a1);
        }
    }
    int row0 = (bl0 + tok0) * 256 + c;
    int row1 = (bl0 + tok1) * 256 + c;
    if (MODE == 0) {
        float4 bb = *(const float4*)(b1 + b * 256 + c);
        float4 z0 = {a0.x + bb.x, a0.y + bb.y, a0.z + bb.z, a0.w + bb.w};
        float4 z1 = {a1.x + bb.x, a1.y + bb.y, a1.z + bb.z, a1.w + bb.w};
        *(float4*)(ws + OFF_GZ1 + row0) = z0;
        *(float4*)(ws + OFF_GZ1 + row1) = z1;
        float4 s0 = {silu_f(z0.x), silu_f(z0.y), silu_f(z0.z), silu_f(z0.w)};
        float4 s1 = {silu_f(z1.x), silu_f(z1.y), silu_f(z1.z), silu_f(z1.w)};
        *(float4*)(ws + OFF_X2 + row0) = s0;
        *(float4*)(ws + OFF_X2 + row1) = s1;
    } else if (MODE == 1) {
        float4 bb = *(const float4*)(b2 + b * 256 + c);
        float4 v0 = *(const float4*)(ws + OFF_V + row0);
        float4 v1 = *(const float4*)(ws + OFF_V + row1);
        float4 g0 = {a0.x + bb.x - v0.x, a0.y + bb.y - v0.y,
                     a0.z + bb.z - v0.z, a0.w + bb.w - v0.w};
        float4 g1 = {a1.x + bb.x - v1.x, a1.y + bb.y - v1.y,
                     a1.z + bb.z - v1.z, a1.w + bb.w - v1.w};
        *(float4*)(ws + OFF_GZ2 + row0) = g0;
        *(float4*)(ws + OFF_GZ2 + row1) = g1;
    } else {
        float4 z0 = *(const float4*)(ws + OFF_GZ1 + row0);
        float4 z1 = *(const float4*)(ws + OFF_GZ1 + row1);
        float4 g0, g1;
        {
            float sg;
            sg = 1.0f / (1.0f + expf(-z0.x)); g0.x = a0.x * (sg * (1.0f + z0.x * (1.0f - sg)));
            sg = 1.0f / (1.0f + expf(-z0.y)); g0.y = a0.y * (sg * (1.0f + z0.y * (1.0f - sg)));
            sg = 1.0f / (1.0f + expf(-z0.z)); g0.z = a0.z * (sg * (1.0f + z0.z * (1.0f - sg)));
            sg = 1.0f / (1.0f + expf(-z0.w)); g0.w = a0.w * (sg * (1.0f + z0.w * (1.0f - sg)));
            sg = 1.0f / (1.0f + expf(-z1.x)); g1.x = a1.x * (sg * (1.0f + z1.x * (1.0f - sg)));
            sg = 1.0f / (1.0f + expf(-z1.y)); g1.y = a1.y * (sg * (1.0f + z1.y * (1.0f - sg)));
            sg = 1.0f / (1.0f + expf(-z1.z)); g1.z = a1.z * (sg * (1.0f + z1.z * (1.0f - sg)));
            sg = 1.0f / (1.0f + expf(-z1.w)); g1.w = a1.w * (sg * (1.0f + z1.w * (1.0f - sg)));
        }
        *(float4*)(ws + OFF_GZ1 + row0) = g0;
        *(float4*)(ws + OFF_GZ1 + row1) = g1;
    }
}

// ---------------------------------------------------------------------------
// k5: transpose K and X2 ([B,128,256] -> [B,256,128]) for coalesced scores
// ---------------------------------------------------------------------------
__global__ __launch_bounds__(256) void transpkx_kernel(float* __restrict__ ws) {
    int z = blockIdx.z; int b = z & 1; int mat = z >> 1;
    const float* src = ws + (mat ? OFF_X2 : OFF_K) + b * 32768;
    float* dst = ws + (mat ? OFF_X2T : OFF_KT) + b * 32768;
    __shared__ float tile[32][33];
    int tx = threadIdx.x & 31, ty = threadIdx.x >> 5;
    int l0 = blockIdx.y * 32, n0 = blockIdx.x * 32;
    for (int i = 0; i < 32; i += 8)
        tile[ty + i][tx] = src[(l0 + ty + i) * 256 + (n0 + tx)];
    __syncthreads();
    for (int i = 0; i < 32; i += 8)
        dst[(n0 + ty + i) * 128 + (l0 + tx)] = tile[tx][ty + i];
}

// ---------------------------------------------------------------------------
// k6: scores -> masked P (STAGE1: Q@KT -> P1; STAGE2: XQ@X2T -> P2).
// P[l,m] = (m<=l) ? A[l,m]*lr[m]*(1+S[l,m]) : 0. Tile 16 l x 128 m, 256 thr,
// 2 rows/thread, 8-deep batched KT loads. grid (8 ltiles, B).
// ---------------------------------------------------------------------------
template <int STAGE>
__global__ __launch_bounds__(256) void score_kernel(float* __restrict__ ws) {
    int b = blockIdx.y;
    int l0 = blockIdx.x * 16;
    int t = threadIdx.x;
    const float* Asrc = ws + (STAGE == 1 ? OFF_Q : OFF_XQ) + (b * 128 + l0) * 256;
    const float* Bt   = ws + (STAGE == 1 ? OFF_KT : OFF_X2T) + b * 32768;
    float* P = ws + (STAGE == 1 ? OFF_P1 : OFF_P2) + b * 16384;
    __shared__ float qs[16][260];
    for (int i = t; i < 1024; i += 256) {
        int tok = i >> 6, kq = i & 63;
        *(float4*)&qs[tok][kq * 4] = *(const float4*)(Asrc + tok * 256 + kq * 4);
    }
    __syncthreads();
    int lg = t >> 5, q = t & 31;
    int li0 = 2 * lg, li1 = li0 + 1;
    const float* Bp = Bt + 4 * q;
    float4 s0 = {0, 0, 0, 0}, s1 = {0, 0, 0, 0};
#pragma unroll 2
    for (int d0 = 0; d0 < 256; d0 += 8) {
        float4 kb[8];
#pragma unroll
        for (int kk = 0; kk < 8; ++kk)
            kb[kk] = *(const float4*)(Bp + (d0 + kk) * 128);
#pragma unroll
        for (int kk = 0; kk < 8; ++kk) {
            s0 = fma4(qs[li0][d0 + kk], kb[kk], s0);
            s1 = fma4(qs[li1][d0 + kk], kb[kk], s1);
        }
    }
    float4 L4 = *(const float4*)(ws + OFF_LR + b * 128 + 4 * q);
    int m0 = 4 * q;
    {
        int l = l0 + li0;
        float4 A4 = *(const float4*)(ws + OFF_A + (b * 128 + l) * 128 + m0);
        float4 pv;
        pv.x = (m0 + 0 <= l) ? A4.x * L4.x * (1.0f + s0.x) : 0.0f;
        pv.y = (m0 + 1 <= l) ? A4.y * L4.y * (1.0f + s0.y) : 0.0f;
        pv.z = (m0 + 2 <= l) ? A4.z * L4.z * (1.0f + s0.z) : 0.0f;
        pv.w = (m0 + 3 <= l) ? A4.w * L4.w * (1.0f + s0.w) : 0.0f;
        *(float4*)(P + l * 128 + m0) = pv;
    }
    {
        int l = l0 + li1;
        float4 A4 = *(const float4*)(ws + OFF_A + (b * 128 + l) * 128 + m0);
        float4 pv;
        pv.x = (m0 + 0 <= l) ? A4.x * L4.x * (1.0f + s1.x) : 0.0f;
        pv.y = (m0 + 1 <= l) ? A4.y * L4.y * (1.0f + s1.y) : 0.0f;
        pv.z = (m0 + 2 <= l) ? A4.z * L4.z * (1.0f + s1.z) : 0.0f;
        pv.w = (m0 + 3 <= l) ? A4.w * L4.w * (1.0f + s1.w) : 0.0f;
        *(float4*)(P + l * 128 + m0) = pv;
    }
}

// ---------------------------------------------------------------------------
// k7: combine (STAGE1 -> XQ with silu; STAGE2 -> out ZQ2).
// out = P@G + wd*(A@Wt + bias) - cl*(A@mWt + mbias).
// Tile 8 tok x 128 c, 256 thr (1 tok x 1 quad; u,v,p = 3 indep acc streams;
// 16 loads in flight in the d-loop). grid (2 ctiles, 32 ttiles).
// ---------------------------------------------------------------------------
template <int STAGE>
__global__ __launch_bounds__(256) void combine_kernel(
    const float* __restrict__ bias, const float* __restrict__ mbias,
    float* __restrict__ out, float* __restrict__ ws) {
    int bl0 = blockIdx.y * 8;
    int b = bl0 >> 7, l0 = bl0 & 127;
    int c0 = blockIdx.x * 128;
    int t = threadIdx.x;
    const float* Asrc = ws + (STAGE == 1 ? OFF_Q : OFF_XQ) + bl0 * 256;
    const float* Wt  = ws + (STAGE == 1 ? OFF_W1T  : OFF_W2T)  + b * 65536 + c0;
    const float* mWt = ws + (STAGE == 1 ? OFF_MW1T : OFF_MW2T) + b * 65536 + c0;
    const float* G   = ws + (STAGE == 1 ? OFF_GZ1 : OFF_GZ2) + b * 32768 + c0;
    const float* P   = ws + (STAGE == 1 ? OFF_P1 : OFF_P2) + (b * 128 + l0) * 128;
    __shared__ float qs[8][260];
    __shared__ float ps[8][132];
    for (int i = t; i < 512; i += 256) {
        int tok = i >> 6, kq = i & 63;
        *(float4*)&qs[tok][kq * 4] = *(const float4*)(Asrc + tok * 256 + kq * 4);
    }
    {
        int tok = t >> 5, mq = t & 31;
        *(float4*)&ps[tok][mq * 4] = *(const float4*)(P + tok * 128 + mq * 4);
    }
    __syncthreads();
    int tok = t >> 5, q = t & 31;
    int c = 4 * q;
    float4 u = {0, 0, 0, 0}, v = {0, 0, 0, 0}, p = {0, 0, 0, 0};
    for (int d0 = 0; d0 < 256; d0 += 8) {
        float4 wb[8], mwb[8];
#pragma unroll
        for (int kk = 0; kk < 8; ++kk) {
            wb[kk]  = *(const float4*)(Wt  + (d0 + kk) * 256 + c);
            mwb[kk] = *(const float4*)(mWt + (d0 + kk) * 256 + c);
        }
#pragma unroll
        for (int kk = 0; kk < 8; ++kk) {
            float a = qs[tok][d0 + kk];
            u = fma4(a, wb[kk], u);
            v = fma4(a, mwb[kk], v);
        }
    }
    int mmax = l0 + 8;   // causal: P rows are zero beyond l
    for (int m0 = 0; m0 < mmax; m0 += 8) {
        float4 gb[8];
#pragma unroll
        for (int kk = 0; kk < 8; ++kk)
            gb[kk] = *(const float4*)(G + (m0 + kk) * 256 + c);
#pragma unroll
        for (int kk = 0; kk < 8; ++kk)
            p = fma4(ps[tok][m0 + kk], gb[kk], p);
    }
    int l = l0 + tok;
    float cl = ws[OFF_C + b * 128 + l];
    float wd = ws[OFF_WDCUM + b * 128 + l];
    float4 mb4 = *(const float4*)(mbias + b * 256 + c0 + c);
    float4 bb4 = *(const float4*)(bias  + b * 256 + c0 + c);
    float4 o;
    o.x = p.x - cl * (v.x + mb4.x) + wd * (u.x + bb4.x);
    o.y = p.y - cl * (v.y + mb4.y) + wd * (u.y + bb4.y);
    o.z = p.z - cl * (v.z + mb4.z) + wd * (u.z + bb4.z);
    o.w = p.w - cl * (v.w + mb4.w) + wd * (u.w + bb4.w);
    if (STAGE == 1) {
        o.x = silu_f(o.x); o.y = silu_f(o.y); o.z = silu_f(o.z); o.w = silu_f(o.w);
        *(float4*)(ws + OFF_XQ + (bl0 + tok) * 256 + c0 + c) = o;
    } else {
        *(float4*)(out + OUT_ZQ2 + (bl0 + tok) * 256 + c0 + c) = o;
    }
}

// ---------------------------------------------------------------------------
// k8: last-token weight outputs (W1p/mgW1 fam=0, W2p/mgW2 fam=1)
// ---------------------------------------------------------------------------
__global__ __launch_bounds__(256) void lastw_kernel(
    const float* __restrict__ W1, const float* __restrict__ mW1,
    const float* __restrict__ W2, const float* __restrict__ mW2,
    const float* __restrict__ ws, float* __restrict__ out) {
    int z = blockIdx.z; int b = z >> 1; int fam = z & 1;
    int t = threadIdx.x;
    __shared__ float wa[128], wm[128];
    __shared__ float LA[128][16], LM[128][16], R[128][16];
    const float* lr = ws + OFF_LR + b * Ln;
    const float* Pm = ws + OFF_PM + b * Ln;
    const float* Arow = ws + OFF_A + (b * Ln + Ln - 1) * Ln;
    if (t < 128) {
        wa[t] = Arow[t] * lr[t];
        wm[t] = expf(Pm[Ln - 1] - Pm[t]) * lr[t];
    }
    const float* left  = ws + (fam == 0 ? OFF_GZ1 : OFF_GZ2) + b * Ln * 256;
    const float* right = ws + (fam == 0 ? OFF_K   : OFF_X2 ) + b * Ln * 256;
    int i0 = blockIdx.y * 16, j0 = blockIdx.x * 16;
    __syncthreads();
    for (int e = t; e < 2048; e += 256) {
        int m = e >> 4, i = e & 15;
        float lv = left[m * 256 + i0 + i];
        LA[m][i] = wa[m] * lv;
        LM[m][i] = wm[m] * lv;
        R[m][i]  = right[m * 256 + j0 + i];
    }
    __syncthreads();
    int tx = t & 15, ty = t >> 4;
    float accA = 0.0f, accM = 0.0f;
#pragma unroll 4
    for (int m = 0; m < 128; ++m) {
        accA += LA[m][ty] * R[m][tx];
        accM += LM[m][ty] * R[m][tx];
    }
    float c_last  = ws[OFF_C + b * Ln + Ln - 1];
    float wd_last = ws[OFF_WDCUM + b * Ln + Ln - 1];
    float mc_last = ws[OFF_MOMCUM + b * Ln + Ln - 1];
    int i = i0 + ty, j = j0 + tx;
    const float* base1 = (fam == 0 ? W1 : W2) + b * 65536;
    const float* basem = (fam == 0 ? mW1 : mW2) + b * 65536;
    float b1v = base1[i * 256 + j], bmv = basem[i * 256 + j];
    int op = (fam == 0 ? OUT_W1P : OUT_W2P) + (b * 256 + i) * 256 + j;
    int om = (fam == 0 ? OUT_MGW1 : OUT_MGW2) + (b * 256 + i) * 256 + j;
    out[op] = accA - c_last * bmv + wd_last * b1v;
    out[om] = accM - mc_last * bmv;
}

// ---------------------------------------------------------------------------
// k9: last-token bias outputs
// ---------------------------------------------------------------------------
__global__ __launch_bounds__(256) void lastb_kernel(
    const float* __restrict__ b1, const float* __restrict__ mb1,
    const float* __restrict__ b2, const float* __restrict__ mb2,
    const float* __restrict__ ws, float* __restrict__ out) {
    int b = blockIdx.x; int t = threadIdx.x;
    __shared__ float wa[128], wm[128];
    if (t < 128) {
        wa[t] = ws[OFF_A + (b * Ln + Ln - 1) * Ln + t] * ws[OFF_LR + b * Ln + t];
        wm[t] = expf(ws[OFF_PM + b * Ln + Ln - 1] - ws[OFF_PM + b * Ln + t]) *
                ws[OFF_LR + b * Ln + t];
    }
    __syncthreads();
    const float* gz1 = ws + OFF_GZ1 + b * Ln * 256;
    const float* gz2 = ws + OFF_GZ2 + b * Ln * 256;
    float sA1 = 0, sM1 = 0, sA2 = 0, sM2 = 0;
#pragma unroll 4
    for (int m = 0; m < 128; ++m) {
        float g1 = gz1[m * 256 + t], g2 = gz2[m * 256 + t];
        sA1 += wa[m] * g1; sM1 += wm[m] * g1;
        sA2 += wa[m] * g2; sM2 += wm[m] * g2;
    }
    float c_last  = ws[OFF_C + b * Ln + Ln - 1];
    float wd_last = ws[OFF_WDCUM + b * Ln + Ln - 1];
    float mc_last = ws[OFF_MOMCUM + b * Ln + Ln - 1];
    out[OUT_B1P + b * 256 + t]  = sA1 - c_last * mb1[b * 256 + t] + wd_last * b1[b * 256 + t];
    out[OUT_MGB1 + b * 256 + t] = sM1 - mc_last * mb1[b * 256 + t];
    out[OUT_B2P + b * 256 + t]  = sA2 - c_last * mb2[b * 256 + t] + wd_last * b2[b * 256 + t];
    out[OUT_MGB2 + b * 256 + t] = sM2 - mc_last * mb2[b * 256 + t];
}

// ---------------------------------------------------------------------------
extern "C" void kernel_launch(void* const* d_in, const int* in_sizes, int n_in,
                              void* d_out, int out_size, void* d_ws, size_t ws_size,
                              hipStream_t stream) {
    const float* x   = (const float*)d_in[0];
    const float* Wq  = (const float*)d_in[1];
    const float* bq  = (const float*)d_in[2];
    const float* Wk  = (const float*)d_in[3];
    const float* bk  = (const float*)d_in[4];
    const float* Wv  = (const float*)d_in[5];
    const float* bv  = (const float*)d_in[6];
    const float* Wlr = (const float*)d_in[7];
    const float* blr = (const float*)d_in[8];
    const float* Wm  = (const float*)d_in[9];
    const float* bm  = (const float*)d_in[10];
    const float* Wd  = (const float*)d_in[11];
    const float* bd  = (const float*)d_in[12];
    const float* W1  = (const float*)d_in[13];
    const float* b1  = (const float*)d_in[14];
    const float* W2  = (const float*)d_in[15];
    const float* b2  = (const float*)d_in[16];
    const float* mW1 = (const float*)d_in[17];
    const float* mb1 = (const float*)d_in[18];
    const float* mW2 = (const float*)d_in[19];
    const float* mb2 = (const float*)d_in[20];
    float* ws  = (float*)d_ws;
    float* out = (float*)d_out;

    transpose_kernel<<<dim3(8, 8, 8), 256, 0, stream>>>(W1, W2, mW1, mW2, ws);
    qkv_kernel<<<dim3(2, 16, 3), 256, 0, stream>>>(x, Wq, bq, Wk, bk, Wv, bv, ws);
    scalproj_kernel<<<64, 256, 0, stream>>>(x, Wlr, blr, Wm, bm, Wd, bd, ws);
    scan_kernel<<<Bn, 128, 0, stream>>>(ws);
    a_kernel<<<Bn * Ln, 128, 0, stream>>>(ws);
    fstage_kernel<0><<<dim3(2, 16), 256, 0, stream>>>(W2, b1, b2, ws);
    fstage_kernel<1><<<dim3(2, 16), 256, 0, stream>>>(W2, b1, b2, ws);
    fstage_kernel<2><<<dim3(2, 16), 256, 0, stream>>>(W2, b1, b2, ws);
    transpkx_kernel<<<dim3(8, 4, 4), 256, 0, stream>>>(ws);
    score_kernel<1><<<dim3(8, Bn), 256, 0, stream>>>(ws);
    combine_kernel<1><<<dim3(2, 32), 256, 0, stream>>>(b1, mb1, nullptr, ws);
    score_kernel<2><<<dim3(8, Bn), 256, 0, stream>>>(ws);
    combine_kernel<2><<<dim3(2, 32), 256, 0, stream>>>(b2, mb2, out, ws);
    lastw_kernel<<<dim3(16, 16, Bn * 2), 256, 0, stream>>>(W1, mW1, W2, mW2, ws, out);
    lastb_kernel<<<Bn, 256, 0, stream>>>(b1, mb1, b2, mb2, ws, out);
}

// Round 3
// 277.864 us; speedup vs baseline: 1.2999x; 1.2999x over previous
//
#include <hip/hip_runtime.h>
#include <math.h>

// Problem constants
constexpr int Bn = 2, Ln = 128, Dn = 256, Hn = 256;

// log(expm1(0.01))
#define LR_SHIFT (-4.6001660040607144f)

// Workspace offsets (floats)
constexpr int OFF_Q      = 0;        // [B,L,D]
constexpr int OFF_K      = 65536;    // [B,L,D]
constexpr int OFF_V      = 131072;   // [B,L,D]
constexpr int OFF_X2     = 196608;   // [B,L,H]
constexpr int OFF_GZ1    = 262144;   // [B,L,H]  final gZ1
constexpr int OFF_GZ2    = 327680;   // [B,L,D]
constexpr int OFF_KT     = 458752;   // [B,256,128]  K transposed (feature-major)
constexpr int OFF_A      = 524288;   // [B,L,L]  A = Dm@M (lower-tri)
constexpr int OFF_W1T    = 557056;   // [B,D,H]  W1 transposed
constexpr int OFF_W2T    = 688128;   // [B,H,D]  W2 transposed
constexpr int OFF_MW1T   = 819200;   // [B,D,H]
constexpr int OFF_MW2T   = 950272;   // [B,H,D]
constexpr int OFF_LR     = 1081344;  // [B,L]
constexpr int OFF_PM     = 1081600;  // [B,L] prefix sum of log_mom (inclusive)
constexpr int OFF_PD     = 1081856;  // [B,L] prefix sum of log_wd
constexpr int OFF_MOMCUM = 1082112;  // [B,L]
constexpr int OFF_WDCUM  = 1082368;  // [B,L]
constexpr int OFF_C      = 1082624;  // [B,L]  c = Dm @ mom_cum
constexpr int OFF_LOGM   = 1082880;  // [B,L]
constexpr int OFF_LOGWD  = 1083136;  // [B,L]
constexpr int OFF_X2T    = 1083392;  // [B,256,128]  X2 transposed
// total 1148928 floats ~= 4.6 MB

// Output offsets (floats), tuple order
constexpr int OUT_ZQ2  = 0;       // [B,L,D]
constexpr int OUT_W1P  = 65536;   // [B,H,D]
constexpr int OUT_B1P  = 196608;  // [B,H]
constexpr int OUT_W2P  = 197120;  // [B,D,H]
constexpr int OUT_B2P  = 328192;  // [B,D]
constexpr int OUT_MGW1 = 328704;  // [B,H,D]
constexpr int OUT_MGB1 = 459776;  // [B,H]
constexpr int OUT_MGW2 = 460288;  // [B,D,H]
constexpr int OUT_MGB2 = 591360;  // [B,D]

__device__ __forceinline__ float softplus_f(float z) {
    return fmaxf(z, 0.0f) + log1pf(expf(-fabsf(z)));
}

__device__ __forceinline__ float4 fma4(float s, const float4 w, float4 a) {
    a.x += s * w.x; a.y += s * w.y; a.z += s * w.z; a.w += s * w.w; return a;
}

__device__ __forceinline__ float silu_f(float z) {
    return z / (1.0f + expf(-z));
}

__device__ __forceinline__ float dsilu_mul(float a, float z) {
    float sg = 1.0f / (1.0f + expf(-z));
    return a * (sg * (1.0f + z * (1.0f - sg)));
}

// ---------------------------------------------------------------------------
// LAUNCH 1: prep = weight transposes (512 blk) + QKV gemm (96 blk) +
//           scalar projections (64 blk). All depend only on external inputs.
// ---------------------------------------------------------------------------
__global__ __launch_bounds__(256) void prep_kernel(
    const float* __restrict__ x,
    const float* __restrict__ Wq, const float* __restrict__ bq,
    const float* __restrict__ Wk, const float* __restrict__ bk,
    const float* __restrict__ Wv, const float* __restrict__ bv,
    const float* __restrict__ Wlr, const float* __restrict__ blr,
    const float* __restrict__ Wm, const float* __restrict__ bm,
    const float* __restrict__ Wd, const float* __restrict__ bd,
    const float* __restrict__ W1, const float* __restrict__ W2,
    const float* __restrict__ mW1, const float* __restrict__ mW2,
    float* __restrict__ ws) {
    __shared__ float smem[4160];
    int id = blockIdx.x, t = threadIdx.x;
    if (id < 512) {
        // ---- weight transpose: 4 mats x 2 b x (8x8 32-tiles) ----
        int z = id >> 6; int mat = z >> 1; int b = z & 1;
        const float* src; float* dst;
        if (mat == 0)      { src = W1  + b * 65536; dst = ws + OFF_W1T  + b * 65536; }
        else if (mat == 1) { src = W2  + b * 65536; dst = ws + OFF_W2T  + b * 65536; }
        else if (mat == 2) { src = mW1 + b * 65536; dst = ws + OFF_MW1T + b * 65536; }
        else               { src = mW2 + b * 65536; dst = ws + OFF_MW2T + b * 65536; }
        float (*tile)[33] = (float (*)[33])smem;
        int tx = t & 31, ty = t >> 5;
        int tid = id & 63;
        int r0 = (tid >> 3) * 32, c0 = (tid & 7) * 32;
        for (int i = 0; i < 32; i += 8)
            tile[ty + i][tx] = src[(r0 + ty + i) * 256 + (c0 + tx)];
        __syncthreads();
        for (int i = 0; i < 32; i += 8)
            dst[(c0 + ty + i) * 256 + (r0 + tx)] = tile[tx][ty + i];
    } else if (id < 608) {
        // ---- QKV: 3 mats x 2 ctiles x 16 ttiles; 16 tok x 128 col tile ----
        int u = id - 512; int mat = u >> 5; int rem = u & 31;
        int c0 = (rem >> 4) * 128; int bl0 = (rem & 15) * 16;
        const float* W    = (mat == 0) ? Wq : (mat == 1) ? Wk : Wv;
        const float* bias = (mat == 0) ? bq : (mat == 1) ? bk : bv;
        int outoff = (mat == 0) ? OFF_Q : (mat == 1) ? OFF_K : OFF_V;
        float (*xs)[260] = (float (*)[260])smem;
        for (int i = t; i < 1024; i += 256) {
            int tok = i >> 6, kq = i & 63;
            *(float4*)&xs[tok][kq * 4] = *(const float4*)(x + (bl0 + tok) * 256 + kq * 4);
        }
        __syncthreads();
        int tg = t >> 5, q = t & 31;
        int tok0 = 2 * tg, tok1 = tok0 + 1;
        int c = c0 + 4 * q;
        const float* Wp = W + c;
        float4 a0 = {0, 0, 0, 0}, a1 = {0, 0, 0, 0};
#pragma unroll 2
        for (int k0 = 0; k0 < 256; k0 += 8) {
            float4 wb[8];
#pragma unroll
            for (int kk = 0; kk < 8; ++kk)
                wb[kk] = *(const float4*)(Wp + (k0 + kk) * 256);
#pragma unroll
            for (int kk = 0; kk < 8; ++kk) {
                a0 = fma4(xs[tok0][k0 + kk], wb[kk], a0);
                a1 = fma4(xs[tok1][k0 + kk], wb[kk], a1);
            }
        }
        float4 bb = *(const float4*)(bias + c);
        a0.x += bb.x; a0.y += bb.y; a0.z += bb.z; a0.w += bb.w;
        a1.x += bb.x; a1.y += bb.y; a1.z += bb.z; a1.w += bb.w;
        *(float4*)(ws + outoff + (bl0 + tok0) * 256 + c) = a0;
        *(float4*)(ws + outoff + (bl0 + tok1) * 256 + c) = a1;
    } else {
        // ---- scalar projections: 64 blocks x 4 tokens (1 wave each) ----
        int blk = id - 608;
        int ln = t & 63, wv = t >> 6;
        int bl = blk * 4 + wv;
        float4 xv = *(const float4*)(x + bl * 256 + ln * 4);
        float4 wl = *(const float4*)(Wlr + ln * 4);
        float4 wm = *(const float4*)(Wm + ln * 4);
        float4 wd = *(const float4*)(Wd + ln * 4);
        float s1 = xv.x * wl.x + xv.y * wl.y + xv.z * wl.z + xv.w * wl.w;
        float s2 = xv.x * wm.x + xv.y * wm.y + xv.z * wm.z + xv.w * wm.w;
        float s3 = xv.x * wd.x + xv.y * wd.y + xv.z * wd.z + xv.w * wd.w;
#pragma unroll
        for (int off = 32; off > 0; off >>= 1) {
            s1 += __shfl_xor(s1, off);
            s2 += __shfl_xor(s2, off);
            s3 += __shfl_xor(s3, off);
        }
        if (ln == 0) {
            ws[OFF_LR + bl]    = softplus_f(s1 + blr[0] + LR_SHIFT);
            ws[OFF_LOGM + bl]  = -softplus_f(-(s2 + bm[0]));
            ws[OFF_LOGWD + bl] = -softplus_f(s3 + bd[0]);
        }
    }
}

// ---------------------------------------------------------------------------
// LAUNCH 2: mid = fused fast-weight MLP fwd+bwd (32 blk) + scan+A (256 blk).
// fwd block: 8 tokens, all 256 cols. K->LDS; Z1,X2,gZ2 live in LDS across
// the 3 stages; KT/X2T written straight from LDS (transpkx eliminated).
// ---------------------------------------------------------------------------
__global__ __launch_bounds__(256) void mid_kernel(
    const float* __restrict__ W2nat, const float* __restrict__ b1,
    const float* __restrict__ b2, float* __restrict__ ws) {
    __shared__ float smem[8320];
    int id = blockIdx.x, t = threadIdx.x;
    if (id < 32) {
        int bl0 = id * 8;
        int b = bl0 >> 7;
        float (*ks)[260] = (float (*)[260])smem;             // K
        float (*zs)[260] = (float (*)[260])(smem + 2080);    // Z1
        float (*as)[260] = (float (*)[260])(smem + 4160);    // X2
        float (*gs)[260] = (float (*)[260])(smem + 6240);    // gZ2
        for (int i = t; i < 512; i += 256) {
            int tok = i >> 6, kq = i & 63;
            *(float4*)&ks[tok][kq * 4] =
                *(const float4*)(ws + OFF_K + (bl0 + tok) * 256 + kq * 4);
        }
        __syncthreads();
        int tok = t >> 5, q = t & 31;
        int c = 4 * q, c2 = c + 128;
        // ---- stage 0: Z1 = K @ W1t + b1; X2 = silu(Z1) ----
        {
            const float* W1t = ws + OFF_W1T + b * 65536;
            float4 a0 = {0, 0, 0, 0}, a1 = {0, 0, 0, 0};
            for (int k0 = 0; k0 < 256; k0 += 8) {
                float4 w0[8], w1[8];
#pragma unroll
                for (int kk = 0; kk < 8; ++kk) {
                    w0[kk] = *(const float4*)(W1t + (k0 + kk) * 256 + c);
                    w1[kk] = *(const float4*)(W1t + (k0 + kk) * 256 + c2);
                }
#pragma unroll
                for (int kk = 0; kk < 8; ++kk) {
                    float kv = ks[tok][k0 + kk];
                    a0 = fma4(kv, w0[kk], a0);
                    a1 = fma4(kv, w1[kk], a1);
                }
            }
            float4 bb0 = *(const float4*)(b1 + b * 256 + c);
            float4 bb1 = *(const float4*)(b1 + b * 256 + c2);
            float4 z0 = {a0.x + bb0.x, a0.y + bb0.y, a0.z + bb0.z, a0.w + bb0.w};
            float4 z1 = {a1.x + bb1.x, a1.y + bb1.y, a1.z + bb1.z, a1.w + bb1.w};
            *(float4*)&zs[tok][c]  = z0;
            *(float4*)&zs[tok][c2] = z1;
            float4 s0 = {silu_f(z0.x), silu_f(z0.y), silu_f(z0.z), silu_f(z0.w)};
            float4 s1 = {silu_f(z1.x), silu_f(z1.y), silu_f(z1.z), silu_f(z1.w)};
            *(float4*)&as[tok][c]  = s0;
            *(float4*)&as[tok][c2] = s1;
            *(float4*)(ws + OFF_X2 + (bl0 + tok) * 256 + c)  = s0;
            *(float4*)(ws + OFF_X2 + (bl0 + tok) * 256 + c2) = s1;
        }
        __syncthreads();
        // ---- KT / X2T transposed writes (from LDS; n = t) ----
        {
            int l0b = bl0 & 127;
            float v0[8], v1[8];
#pragma unroll
            for (int j = 0; j < 8; ++j) { v0[j] = ks[j][t]; v1[j] = as[j][t]; }
            float* KTp  = ws + OFF_KT  + b * 32768 + t * 128 + l0b;
            float* X2Tp = ws + OFF_X2T + b * 32768 + t * 128 + l0b;
            float4 p0 = {v0[0], v0[1], v0[2], v0[3]};
            float4 p1 = {v0[4], v0[5], v0[6], v0[7]};
            *(float4*)KTp = p0; *(float4*)(KTp + 4) = p1;
            float4 r0 = {v1[0], v1[1], v1[2], v1[3]};
            float4 r1 = {v1[4], v1[5], v1[6], v1[7]};
            *(float4*)X2Tp = r0; *(float4*)(X2Tp + 4) = r1;
        }
        // ---- stage 1: gZ2 = X2 @ W2t + b2 - V ----
        {
            const float* W2t = ws + OFF_W2T + b * 65536;
            float4 a0 = {0, 0, 0, 0}, a1 = {0, 0, 0, 0};
            for (int k0 = 0; k0 < 256; k0 += 8) {
                float4 w0[8], w1[8];
#pragma unroll
                for (int kk = 0; kk < 8; ++kk) {
                    w0[kk] = *(const float4*)(W2t + (k0 + kk) * 256 + c);
                    w1[kk] = *(const float4*)(W2t + (k0 + kk) * 256 + c2);
                }
#pragma unroll
                for (int kk = 0; kk < 8; ++kk) {
                    float xv = as[tok][k0 + kk];
                    a0 = fma4(xv, w0[kk], a0);
                    a1 = fma4(xv, w1[kk], a1);
                }
            }
            float4 bb0 = *(const float4*)(b2 + b * 256 + c);
            float4 bb1 = *(const float4*)(b2 + b * 256 + c2);
            float4 v0 = *(const float4*)(ws + OFF_V + (bl0 + tok) * 256 + c);
            float4 v1 = *(const float4*)(ws + OFF_V + (bl0 + tok) * 256 + c2);
            float4 g0 = {a0.x + bb0.x - v0.x, a0.y + bb0.y - v0.y,
                         a0.z + bb0.z - v0.z, a0.w + bb0.w - v0.w};
            float4 g1 = {a1.x + bb1.x - v1.x, a1.y + bb1.y - v1.y,
                         a1.z + bb1.z - v1.z, a1.w + bb1.w - v1.w};
            *(float4*)&gs[tok][c]  = g0;
            *(float4*)&gs[tok][c2] = g1;
            *(float4*)(ws + OFF_GZ2 + (bl0 + tok) * 256 + c)  = g0;
            *(float4*)(ws + OFF_GZ2 + (bl0 + tok) * 256 + c2) = g1;
        }
        __syncthreads();
        // ---- stage 2: gX2 = gZ2 @ W2(native); gZ1 = gX2 * silu'(Z1) ----
        {
            const float* W2n = W2nat + b * 65536;
            float4 a0 = {0, 0, 0, 0}, a1 = {0, 0, 0, 0};
            for (int k0 = 0; k0 < 256; k0 += 8) {
                float4 w0[8], w1[8];
#pragma unroll
                for (int kk = 0; kk < 8; ++kk) {
                    w0[kk] = *(const float4*)(W2n + (k0 + kk) * 256 + c);
                    w1[kk] = *(const float4*)(W2n + (k0 + kk) * 256 + c2);
                }
#pragma unroll
                for (int kk = 0; kk < 8; ++kk) {
                    float gv = gs[tok][k0 + kk];
                    a0 = fma4(gv, w0[kk], a0);
                    a1 = fma4(gv, w1[kk], a1);
                }
            }
            float4 z0 = *(float4*)&zs[tok][c];
            float4 z1 = *(float4*)&zs[tok][c2];
            float4 g0 = {dsilu_mul(a0.x, z0.x), dsilu_mul(a0.y, z0.y),
                         dsilu_mul(a0.z, z0.z), dsilu_mul(a0.w, z0.w)};
            float4 g1 = {dsilu_mul(a1.x, z1.x), dsilu_mul(a1.y, z1.y),
                         dsilu_mul(a1.z, z1.z), dsilu_mul(a1.w, z1.w)};
            *(float4*)(ws + OFF_GZ1 + (bl0 + tok) * 256 + c)  = g0;
            *(float4*)(ws + OFF_GZ1 + (bl0 + tok) * 256 + c2) = g1;
        }
    } else {
        // ---- scan + A-row: block (b,l) recomputes the 128-wide scans in LDS
        int u = id - 32; int b = u >> 7; int l = u & 127;
        float* sm = smem;
        float* sd = smem + 128;
        float* se = smem + 256;
        if (t < 128) {
            sm[t] = ws[OFF_LOGM + b * Ln + t];
            sd[t] = ws[OFF_LOGWD + b * Ln + t];
        }
        __syncthreads();
        for (int off = 1; off < 128; off <<= 1) {
            float am = 0.0f, ad = 0.0f;
            if (t < 128 && t >= off) { am = sm[t - off]; ad = sd[t - off]; }
            __syncthreads();
            if (t < 128) { sm[t] += am; sd[t] += ad; }
            __syncthreads();
        }
        if (l == 0) {
            if (t < 128) {
                float pm = sm[t], pd = sd[t];
                ws[OFF_PM + b * Ln + t] = pm;
                ws[OFF_PD + b * Ln + t] = pd;
                ws[OFF_MOMCUM + b * Ln + t] = expf(pm);
                ws[OFF_WDCUM + b * Ln + t]  = expf(pd);
                se[t] = expf(pm - pd);
            }
            __syncthreads();
            for (int off = 1; off < 128; off <<= 1) {
                float a = 0.0f;
                if (t < 128 && t >= off) a = se[t - off];
                __syncthreads();
                if (t < 128) se[t] += a;
                __syncthreads();
            }
            if (t < 128) ws[OFF_C + b * Ln + t] = expf(sd[t]) * se[t];
        }
        if (t < 128) {
            int m1 = t;
            float a = 0.0f;
            if (m1 <= l) {
                float pdl = sd[l], pmm1 = sm[m1];
                float s = 0.0f;
                for (int m = m1; m <= l; ++m)
                    s += expf((pdl - sd[m]) + (sm[m] - pmm1));
                a = s;
            }
            ws[OFF_A + (b * Ln + l) * Ln + m1] = a;
        }
    }
}

// ---------------------------------------------------------------------------
// LAUNCH 3: final = fused zq (score1+combine1+score2+combine2, 32 blk; XQ and
// P never leave LDS) + lastw (1024 blk) + lastb (2 blk).
// ---------------------------------------------------------------------------
__global__ __launch_bounds__(256) void final_kernel(
    const float* __restrict__ W1, const float* __restrict__ mW1,
    const float* __restrict__ W2nat, const float* __restrict__ mW2,
    const float* __restrict__ b1, const float* __restrict__ mb1,
    const float* __restrict__ b2, const float* __restrict__ mb2,
    float* __restrict__ out, float* __restrict__ ws) {
    __shared__ float smem[6400];
    int id = blockIdx.x, t = threadIdx.x;
    if (id < 32) {
        int b = id >> 4; int l0 = (id & 15) * 8; int bl0 = b * 128 + l0;
        float (*qs)[260]  = (float (*)[260])smem;            // Q rows
        float (*xqs)[260] = (float (*)[260])(smem + 2080);   // XQ rows
        float (*ps)[132]  = (float (*)[132])(smem + 4160);   // masked P
        for (int i = t; i < 512; i += 256) {
            int tok = i >> 6, kq = i & 63;
            *(float4*)&qs[tok][kq * 4] =
                *(const float4*)(ws + OFF_Q + (bl0 + tok) * 256 + kq * 4);
        }
        __syncthreads();
        int tok = t >> 5;
        int l = l0 + tok;
        float cl  = ws[OFF_C + b * 128 + l];
        float wdc = ws[OFF_WDCUM + b * 128 + l];
        int mmax = l0 + 8;
        // ---- score1: P1 = mask . A*lr*(1 + Q.K^T) ----
        {
            int mq = t & 31, m0 = 4 * mq;
            const float* KT = ws + OFF_KT + b * 32768 + m0;
            float4 s = {0, 0, 0, 0};
            for (int d0 = 0; d0 < 256; d0 += 8) {
                float4 kb[8];
#pragma unroll
                for (int kk = 0; kk < 8; ++kk)
                    kb[kk] = *(const float4*)(KT + (d0 + kk) * 128);
#pragma unroll
                for (int kk = 0; kk < 8; ++kk)
                    s = fma4(qs[tok][d0 + kk], kb[kk], s);
            }
            float4 A4 = *(const float4*)(ws + OFF_A + (b * 128 + l) * 128 + m0);
            float4 L4 = *(const float4*)(ws + OFF_LR + b * 128 + m0);
            float4 pv;
            pv.x = (m0 + 0 <= l) ? A4.x * L4.x * (1.0f + s.x) : 0.0f;
            pv.y = (m0 + 1 <= l) ? A4.y * L4.y * (1.0f + s.y) : 0.0f;
            pv.z = (m0 + 2 <= l) ? A4.z * L4.z * (1.0f + s.z) : 0.0f;
            pv.w = (m0 + 3 <= l) ? A4.w * L4.w * (1.0f + s.w) : 0.0f;
            *(float4*)&ps[tok][m0] = pv;
        }
        __syncthreads();
        // ---- combine1 -> XQ (LDS only) ----
        {
            int q = t & 31;
            for (int half = 0; half < 2; ++half) {
                int c = 4 * q + 128 * half;
                const float* Wt  = ws + OFF_W1T  + b * 65536 + c;
                const float* mWt = ws + OFF_MW1T + b * 65536 + c;
                float4 uacc = {0, 0, 0, 0}, vacc = {0, 0, 0, 0};
                for (int d0 = 0; d0 < 256; d0 += 8) {
                    float4 wb[8], mwb[8];
#pragma unroll
                    for (int kk = 0; kk < 8; ++kk) {
                        wb[kk]  = *(const float4*)(Wt  + (d0 + kk) * 256);
                        mwb[kk] = *(const float4*)(mWt + (d0 + kk) * 256);
                    }
#pragma unroll
                    for (int kk = 0; kk < 8; ++kk) {
                        float a = qs[tok][d0 + kk];
                        uacc = fma4(a, wb[kk], uacc);
                        vacc = fma4(a, mwb[kk], vacc);
                    }
                }
                float4 p = {0, 0, 0, 0};
                const float* G = ws + OFF_GZ1 + b * 32768 + c;
                for (int m0 = 0; m0 < mmax; m0 += 8) {
                    float4 gb[8];
#pragma unroll
                    for (int kk = 0; kk < 8; ++kk)
                        gb[kk] = *(const float4*)(G + (m0 + kk) * 256);
#pragma unroll
                    for (int kk = 0; kk < 8; ++kk)
                        p = fma4(ps[tok][m0 + kk], gb[kk], p);
                }
                float4 mb4 = *(const float4*)(mb1 + b * 256 + c);
                float4 bb4 = *(const float4*)(b1  + b * 256 + c);
                float4 o;
                o.x = silu_f(p.x - cl * (vacc.x + mb4.x) + wdc * (uacc.x + bb4.x));
                o.y = silu_f(p.y - cl * (vacc.y + mb4.y) + wdc * (uacc.y + bb4.y));
                o.z = silu_f(p.z - cl * (vacc.z + mb4.z) + wdc * (uacc.z + bb4.z));
                o.w = silu_f(p.w - cl * (vacc.w + mb4.w) + wdc * (uacc.w + bb4.w));
                *(float4*)&xqs[tok][c] = o;
            }
        }
        __syncthreads();
        // ---- score2: P2 = mask . A*lr*(1 + XQ.X2^T) ----
        {
            int mq = t & 31, m0 = 4 * mq;
            const float* X2T = ws + OFF_X2T + b * 32768 + m0;
            float4 s = {0, 0, 0, 0};
            for (int d0 = 0; d0 < 256; d0 += 8) {
                float4 kb[8];
#pragma unroll
                for (int kk = 0; kk < 8; ++kk)
                    kb[kk] = *(const float4*)(X2T + (d0 + kk) * 128);
#pragma unroll
                for (int kk = 0; kk < 8; ++kk)
                    s = fma4(xqs[tok][d0 + kk], kb[kk], s);
            }
            float4 A4 = *(const float4*)(ws + OFF_A + (b * 128 + l) * 128 + m0);
            float4 L4 = *(const float4*)(ws + OFF_LR + b * 128 + m0);
            float4 pv;
            pv.x = (m0 + 0 <= l) ? A4.x * L4.x * (1.0f + s.x) : 0.0f;
            pv.y = (m0 + 1 <= l) ? A4.y * L4.y * (1.0f + s.y) : 0.0f;
            pv.z = (m0 + 2 <= l) ? A4.z * L4.z * (1.0f + s.z) : 0.0f;
            pv.w = (m0 + 3 <= l) ? A4.w * L4.w * (1.0f + s.w) : 0.0f;
            *(float4*)&ps[tok][m0] = pv;
        }
        __syncthreads();
        // ---- combine2 -> out ZQ2 ----
        {
            int q = t & 31;
            for (int half = 0; half < 2; ++half) {
                int c = 4 * q + 128 * half;
                const float* Wt  = ws + OFF_W2T  + b * 65536 + c;
                const float* mWt = ws + OFF_MW2T + b * 65536 + c;
                float4 uacc = {0, 0, 0, 0}, vacc = {0, 0, 0, 0};
                for (int d0 = 0; d0 < 256; d0 += 8) {
                    float4 wb[8], mwb[8];
#pragma unroll
                    for (int kk = 0; kk < 8; ++kk) {
                        wb[kk]  = *(const float4*)(Wt  + (d0 + kk) * 256);
                        mwb[kk] = *(const float4*)(mWt + (d0 + kk) * 256);
                    }
#pragma unroll
                    for (int kk = 0; kk < 8; ++kk) {
                        float a = xqs[tok][d0 + kk];
                        uacc = fma4(a, wb[kk], uacc);
                        vacc = fma4(a, mwb[kk], vacc);
                    }
                }
                float4 p = {0, 0, 0, 0};
                const float* G = ws + OFF_GZ2 + b * 32768 + c;
                for (int m0 = 0; m0 < mmax; m0 += 8) {
                    float4 gb[8];
#pragma unroll
                    for (int kk = 0; kk < 8; ++kk)
                        gb[kk] = *(const float4*)(G + (m0 + kk) * 256);
#pragma unroll
                    for (int kk = 0; kk < 8; ++kk)
                        p = fma4(ps[tok][m0 + kk], gb[kk], p);
                }
                float4 mb4 = *(const float4*)(mb2 + b * 256 + c);
                float4 bb4 = *(const float4*)(b2  + b * 256 + c);
                float4 o;
                o.x = p.x - cl * (vacc.x + mb4.x) + wdc * (uacc.x + bb4.x);
                o.y = p.y - cl * (vacc.y + mb4.y) + wdc * (uacc.y + bb4.y);
                o.z = p.z - cl * (vacc.z + mb4.z) + wdc * (uacc.z + bb4.z);
                o.w = p.w - cl * (vacc.w + mb4.w) + wdc * (uacc.w + bb4.w);
                *(float4*)(out + OUT_ZQ2 + (bl0 + tok) * 256 + c) = o;
            }
        }
    } else if (id < 1056) {
        // ---- lastw: last-token weight outputs ----
        int u = id - 32; int z = u >> 8; int rem = u & 255;
        int b = z >> 1; int fam = z & 1;
        int i0 = (rem >> 4) * 16, j0 = (rem & 15) * 16;
        float* wa = smem;
        float* wm = smem + 128;
        float (*LA)[16] = (float (*)[16])(smem + 256);
        float (*LM)[16] = (float (*)[16])(smem + 256 + 2048);
        float (*R)[16]  = (float (*)[16])(smem + 256 + 4096);
        const float* lr = ws + OFF_LR + b * Ln;
        const float* Pm = ws + OFF_PM + b * Ln;
        const float* Arow = ws + OFF_A + (b * Ln + Ln - 1) * Ln;
        if (t < 128) {
            wa[t] = Arow[t] * lr[t];
            wm[t] = expf(Pm[Ln - 1] - Pm[t]) * lr[t];
        }
        const float* left  = ws + (fam == 0 ? OFF_GZ1 : OFF_GZ2) + b * Ln * 256;
        const float* right = ws + (fam == 0 ? OFF_K   : OFF_X2 ) + b * Ln * 256;
        __syncthreads();
        for (int e = t; e < 2048; e += 256) {
            int m = e >> 4, i = e & 15;
            float lv = left[m * 256 + i0 + i];
            LA[m][i] = wa[m] * lv;
            LM[m][i] = wm[m] * lv;
            R[m][i]  = right[m * 256 + j0 + i];
        }
        __syncthreads();
        int tx = t & 15, ty = t >> 4;
        float accA = 0.0f, accM = 0.0f;
#pragma unroll 4
        for (int m = 0; m < 128; ++m) {
            accA += LA[m][ty] * R[m][tx];
            accM += LM[m][ty] * R[m][tx];
        }
        float c_last  = ws[OFF_C + b * Ln + Ln - 1];
        float wd_last = ws[OFF_WDCUM + b * Ln + Ln - 1];
        float mc_last = ws[OFF_MOMCUM + b * Ln + Ln - 1];
        int i = i0 + ty, j = j0 + tx;
        const float* base1 = (fam == 0 ? W1 : W2nat) + b * 65536;
        const float* basem = (fam == 0 ? mW1 : mW2) + b * 65536;
        float b1v = base1[i * 256 + j], bmv = basem[i * 256 + j];
        int op = (fam == 0 ? OUT_W1P : OUT_W2P) + (b * 256 + i) * 256 + j;
        int om = (fam == 0 ? OUT_MGW1 : OUT_MGW2) + (b * 256 + i) * 256 + j;
        out[op] = accA - c_last * bmv + wd_last * b1v;
        out[om] = accM - mc_last * bmv;
    } else {
        // ---- lastb: last-token bias outputs ----
        int b = id - 1056;
        float* wa = smem;
        float* wm = smem + 128;
        if (t < 128) {
            wa[t] = ws[OFF_A + (b * Ln + Ln - 1) * Ln + t] * ws[OFF_LR + b * Ln + t];
            wm[t] = expf(ws[OFF_PM + b * Ln + Ln - 1] - ws[OFF_PM + b * Ln + t]) *
                    ws[OFF_LR + b * Ln + t];
        }
        __syncthreads();
        const float* gz1 = ws + OFF_GZ1 + b * Ln * 256;
        const float* gz2 = ws + OFF_GZ2 + b * Ln * 256;
        float sA1 = 0, sM1 = 0, sA2 = 0, sM2 = 0;
#pragma unroll 4
        for (int m = 0; m < 128; ++m) {
            float g1 = gz1[m * 256 + t], g2 = gz2[m * 256 + t];
            sA1 += wa[m] * g1; sM1 += wm[m] * g1;
            sA2 += wa[m] * g2; sM2 += wm[m] * g2;
        }
        float c_last  = ws[OFF_C + b * Ln + Ln - 1];
        float wd_last = ws[OFF_WDCUM + b * Ln + Ln - 1];
        float mc_last = ws[OFF_MOMCUM + b * Ln + Ln - 1];
        out[OUT_B1P + b * 256 + t]  = sA1 - c_last * mb1[b * 256 + t] + wd_last * b1[b * 256 + t];
        out[OUT_MGB1 + b * 256 + t] = sM1 - mc_last * mb1[b * 256 + t];
        out[OUT_B2P + b * 256 + t]  = sA2 - c_last * mb2[b * 256 + t] + wd_last * b2[b * 256 + t];
        out[OUT_MGB2 + b * 256 + t] = sM2 - mc_last * mb2[b * 256 + t];
    }
}

// ---------------------------------------------------------------------------
extern "C" void kernel_launch(void* const* d_in, const int* in_sizes, int n_in,
                              void* d_out, int out_size, void* d_ws, size_t ws_size,
                              hipStream_t stream) {
    const float* x   = (const float*)d_in[0];
    const float* Wq  = (const float*)d_in[1];
    const float* bq  = (const float*)d_in[2];
    const float* Wk  = (const float*)d_in[3];
    const float* bk  = (const float*)d_in[4];
    const float* Wv  = (const float*)d_in[5];
    const float* bv  = (const float*)d_in[6];
    const float* Wlr = (const float*)d_in[7];
    const float* blr = (const float*)d_in[8];
    const float* Wm  = (const float*)d_in[9];
    const float* bm  = (const float*)d_in[10];
    const float* Wd  = (const float*)d_in[11];
    const float* bd  = (const float*)d_in[12];
    const float* W1  = (const float*)d_in[13];
    const float* b1  = (const float*)d_in[14];
    const float* W2  = (const float*)d_in[15];
    const float* b2  = (const float*)d_in[16];
    const float* mW1 = (const float*)d_in[17];
    const float* mb1 = (const float*)d_in[18];
    const float* mW2 = (const float*)d_in[19];
    const float* mb2 = (const float*)d_in[20];
    float* ws  = (float*)d_ws;
    float* out = (float*)d_out;

    prep_kernel<<<672, 256, 0, stream>>>(x, Wq, bq, Wk, bk, Wv, bv,
                                         Wlr, blr, Wm, bm, Wd, bd,
                                         W1, W2, mW1, mW2, ws);
    mid_kernel<<<288, 256, 0, stream>>>(W2, b1, b2, ws);
    final_kernel<<<1058, 256, 0, stream>>>(W1, mW1, W2, mW2,
                                           b1, mb1, b2, mb2, out, ws);
}

// Round 4
// 216.372 us; speedup vs baseline: 1.6694x; 1.2842x over previous
//
#include <hip/hip_runtime.h>
#include <math.h>

// Problem constants
constexpr int Bn = 2, Ln = 128, Dn = 256, Hn = 256;

// log(expm1(0.01))
#define LR_SHIFT (-4.6001660040607144f)

// Workspace offsets (floats)
constexpr int OFF_Q      = 0;        // [B,L,D]
constexpr int OFF_K      = 65536;    // [B,L,D]
constexpr int OFF_V      = 131072;   // [B,L,D]  (dead after mid; reused for P2)
constexpr int OFF_X2     = 196608;   // [B,L,H]
constexpr int OFF_GZ1    = 262144;   // [B,L,H]
constexpr int OFF_GZ2    = 327680;   // [B,L,D]
constexpr int OFF_XQ     = 393216;   // [B,L,H]
constexpr int OFF_KT     = 458752;   // [B,256,128]  K transposed
constexpr int OFF_A      = 524288;   // [B,L,L]
constexpr int OFF_W1T    = 557056;   // [B,D,H]
constexpr int OFF_W2T    = 688128;   // [B,H,D]
constexpr int OFF_MW1T   = 819200;   // [B,D,H]
constexpr int OFF_MW2T   = 950272;   // [B,H,D]
constexpr int OFF_LR     = 1081344;  // [B,L]
constexpr int OFF_PM     = 1081600;  // [B,L]
constexpr int OFF_PD     = 1081856;  // [B,L]
constexpr int OFF_MOMCUM = 1082112;  // [B,L]
constexpr int OFF_WDCUM  = 1082368;  // [B,L]
constexpr int OFF_C      = 1082624;  // [B,L]
constexpr int OFF_LOGM   = 1082880;  // [B,L]
constexpr int OFF_LOGWD  = 1083136;  // [B,L]
constexpr int OFF_X2T    = 1083392;  // [B,256,128]
constexpr int OFF_U1     = 1148928;  // [B,L,256]  Q@W1T + b1
constexpr int OFF_V1     = 1214464;  // [B,L,256]  Q@mW1T + mb1
constexpr int OFF_U2     = 1280000;  // [B,L,256]  XQ@W2T + b2
constexpr int OFF_V2     = 1345536;  // [B,L,256]  XQ@mW2T + mb2
constexpr int OFF_P2     = OFF_V;    // [B,128,128] stage-2 masked P
// total 1411072 floats ~= 5.6 MB

// Output offsets (floats), tuple order
constexpr int OUT_ZQ2  = 0;       // [B,L,D]
constexpr int OUT_W1P  = 65536;   // [B,H,D]
constexpr int OUT_B1P  = 196608;  // [B,H]
constexpr int OUT_W2P  = 197120;  // [B,D,H]
constexpr int OUT_B2P  = 328192;  // [B,D]
constexpr int OUT_MGW1 = 328704;  // [B,H,D]
constexpr int OUT_MGB1 = 459776;  // [B,H]
constexpr int OUT_MGW2 = 460288;  // [B,D,H]
constexpr int OUT_MGB2 = 591360;  // [B,D]

__device__ __forceinline__ float softplus_f(float z) {
    return fmaxf(z, 0.0f) + log1pf(expf(-fabsf(z)));
}

__device__ __forceinline__ float4 fma4(float s, const float4 w, float4 a) {
    a.x += s * w.x; a.y += s * w.y; a.z += s * w.z; a.w += s * w.w; return a;
}

__device__ __forceinline__ float silu_f(float z) {
    return z / (1.0f + expf(-z));
}

__device__ __forceinline__ float dsilu_mul(float a, float z) {
    float sg = 1.0f / (1.0f + expf(-z));
    return a * (sg * (1.0f + z * (1.0f - sg)));
}

// 16-token x 128-col GEMM tile: dst[tok,c] = src_row[tok] . W[:,c] + bias[c]
// 16-deep register-batched weight loads.
__device__ __forceinline__ void gemm_tile_16x128(
    const float* __restrict__ srcrow,   // [16 tok][256] rows base (global)
    const float* __restrict__ W,        // [256][256] col-major-out (row k, col c)
    const float* __restrict__ bias,     // [256] or nullptr
    float* __restrict__ dst,            // row base for token 0
    int c0, int t, float* smem) {
    float (*xs)[260] = (float (*)[260])smem;
    for (int i = t; i < 1024; i += 256) {
        int tok = i >> 6, kq = i & 63;
        *(float4*)&xs[tok][kq * 4] = *(const float4*)(srcrow + tok * 256 + kq * 4);
    }
    __syncthreads();
    int tg = t >> 5, q = t & 31;
    int tok0 = 2 * tg, tok1 = tok0 + 1;
    int c = c0 + 4 * q;
    const float* Wp = W + c;
    float4 a0 = {0, 0, 0, 0}, a1 = {0, 0, 0, 0};
    for (int k0 = 0; k0 < 256; k0 += 16) {
        float4 wb[16];
#pragma unroll
        for (int kk = 0; kk < 16; ++kk)
            wb[kk] = *(const float4*)(Wp + (k0 + kk) * 256);
#pragma unroll
        for (int kk = 0; kk < 16; ++kk) {
            a0 = fma4(xs[tok0][k0 + kk], wb[kk], a0);
            a1 = fma4(xs[tok1][k0 + kk], wb[kk], a1);
        }
    }
    if (bias) {
        float4 bb = *(const float4*)(bias + c);
        a0.x += bb.x; a0.y += bb.y; a0.z += bb.z; a0.w += bb.w;
        a1.x += bb.x; a1.y += bb.y; a1.z += bb.z; a1.w += bb.w;
    }
    *(float4*)(dst + tok0 * 256 + c) = a0;
    *(float4*)(dst + tok1 * 256 + c) = a1;
}

// ---------------------------------------------------------------------------
// LAUNCH 1: prep = weight transposes (512) + QKV gemm (96) + scalar proj (64)
// ---------------------------------------------------------------------------
__global__ __launch_bounds__(256) void prep_kernel(
    const float* __restrict__ x,
    const float* __restrict__ Wq, const float* __restrict__ bq,
    const float* __restrict__ Wk, const float* __restrict__ bk,
    const float* __restrict__ Wv, const float* __restrict__ bv,
    const float* __restrict__ Wlr, const float* __restrict__ blr,
    const float* __restrict__ Wm, const float* __restrict__ bm,
    const float* __restrict__ Wd, const float* __restrict__ bd,
    const float* __restrict__ W1, const float* __restrict__ W2,
    const float* __restrict__ mW1, const float* __restrict__ mW2,
    float* __restrict__ ws) {
    __shared__ float smem[4160];
    int id = blockIdx.x, t = threadIdx.x;
    if (id < 512) {
        int z = id >> 6; int mat = z >> 1; int b = z & 1;
        const float* src; float* dst;
        if (mat == 0)      { src = W1  + b * 65536; dst = ws + OFF_W1T  + b * 65536; }
        else if (mat == 1) { src = W2  + b * 65536; dst = ws + OFF_W2T  + b * 65536; }
        else if (mat == 2) { src = mW1 + b * 65536; dst = ws + OFF_MW1T + b * 65536; }
        else               { src = mW2 + b * 65536; dst = ws + OFF_MW2T + b * 65536; }
        float (*tile)[33] = (float (*)[33])smem;
        int tx = t & 31, ty = t >> 5;
        int tid = id & 63;
        int r0 = (tid >> 3) * 32, c0 = (tid & 7) * 32;
        for (int i = 0; i < 32; i += 8)
            tile[ty + i][tx] = src[(r0 + ty + i) * 256 + (c0 + tx)];
        __syncthreads();
        for (int i = 0; i < 32; i += 8)
            dst[(c0 + ty + i) * 256 + (r0 + tx)] = tile[tx][ty + i];
    } else if (id < 608) {
        int u = id - 512; int mat = u >> 5; int rem = u & 31;
        int c0 = (rem >> 4) * 128; int bl0 = (rem & 15) * 16;
        const float* W    = (mat == 0) ? Wq : (mat == 1) ? Wk : Wv;
        const float* bias = (mat == 0) ? bq : (mat == 1) ? bk : bv;
        int outoff = (mat == 0) ? OFF_Q : (mat == 1) ? OFF_K : OFF_V;
        gemm_tile_16x128(x + bl0 * 256, W, bias, ws + outoff + bl0 * 256, c0, t, smem);
    } else {
        int blk = id - 608;
        int ln = t & 63, wv = t >> 6;
        int bl = blk * 4 + wv;
        float4 xv = *(const float4*)(x + bl * 256 + ln * 4);
        float4 wl = *(const float4*)(Wlr + ln * 4);
        float4 wm = *(const float4*)(Wm + ln * 4);
        float4 wd = *(const float4*)(Wd + ln * 4);
        float s1 = xv.x * wl.x + xv.y * wl.y + xv.z * wl.z + xv.w * wl.w;
        float s2 = xv.x * wm.x + xv.y * wm.y + xv.z * wm.z + xv.w * wm.w;
        float s3 = xv.x * wd.x + xv.y * wd.y + xv.z * wd.z + xv.w * wd.w;
#pragma unroll
        for (int off = 32; off > 0; off >>= 1) {
            s1 += __shfl_xor(s1, off);
            s2 += __shfl_xor(s2, off);
            s3 += __shfl_xor(s3, off);
        }
        if (ln == 0) {
            ws[OFF_LR + bl]    = softplus_f(s1 + blr[0] + LR_SHIFT);
            ws[OFF_LOGM + bl]  = -softplus_f(-(s2 + bm[0]));
            ws[OFF_LOGWD + bl] = -softplus_f(s3 + bd[0]);
        }
    }
}

// ---------------------------------------------------------------------------
// LAUNCH 2: mid = fused MLP fwd+bwd (32) + scan/A (256) + U1/V1 GEMM (64)
// ---------------------------------------------------------------------------
__global__ __launch_bounds__(256) void mid_kernel(
    const float* __restrict__ W2nat, const float* __restrict__ b1,
    const float* __restrict__ b2, const float* __restrict__ mb1,
    float* __restrict__ ws) {
    __shared__ float smem[8320];
    int id = blockIdx.x, t = threadIdx.x;
    if (id < 32) {
        int bl0 = id * 8;
        int b = bl0 >> 7;
        float (*ks)[260] = (float (*)[260])smem;             // K
        float (*zs)[260] = (float (*)[260])(smem + 2080);    // Z1
        float (*as)[260] = (float (*)[260])(smem + 4160);    // X2
        float (*gs)[260] = (float (*)[260])(smem + 6240);    // gZ2
        for (int i = t; i < 512; i += 256) {
            int tok = i >> 6, kq = i & 63;
            *(float4*)&ks[tok][kq * 4] =
                *(const float4*)(ws + OFF_K + (bl0 + tok) * 256 + kq * 4);
        }
        __syncthreads();
        int tok = t >> 5, q = t & 31;
        int c = 4 * q, c2 = c + 128;
        // stage 0: Z1 = K @ W1t + b1; X2 = silu(Z1)
        {
            const float* W1t = ws + OFF_W1T + b * 65536;
            float4 a0 = {0, 0, 0, 0}, a1 = {0, 0, 0, 0};
            for (int k0 = 0; k0 < 256; k0 += 8) {
                float4 w0[8], w1[8];
#pragma unroll
                for (int kk = 0; kk < 8; ++kk) {
                    w0[kk] = *(const float4*)(W1t + (k0 + kk) * 256 + c);
                    w1[kk] = *(const float4*)(W1t + (k0 + kk) * 256 + c2);
                }
#pragma unroll
                for (int kk = 0; kk < 8; ++kk) {
                    float kv = ks[tok][k0 + kk];
                    a0 = fma4(kv, w0[kk], a0);
                    a1 = fma4(kv, w1[kk], a1);
                }
            }
            float4 bb0 = *(const float4*)(b1 + b * 256 + c);
            float4 bb1 = *(const float4*)(b1 + b * 256 + c2);
            float4 z0 = {a0.x + bb0.x, a0.y + bb0.y, a0.z + bb0.z, a0.w + bb0.w};
            float4 z1 = {a1.x + bb1.x, a1.y + bb1.y, a1.z + bb1.z, a1.w + bb1.w};
            *(float4*)&zs[tok][c]  = z0;
            *(float4*)&zs[tok][c2] = z1;
            float4 s0 = {silu_f(z0.x), silu_f(z0.y), silu_f(z0.z), silu_f(z0.w)};
            float4 s1 = {silu_f(z1.x), silu_f(z1.y), silu_f(z1.z), silu_f(z1.w)};
            *(float4*)&as[tok][c]  = s0;
            *(float4*)&as[tok][c2] = s1;
            *(float4*)(ws + OFF_X2 + (bl0 + tok) * 256 + c)  = s0;
            *(float4*)(ws + OFF_X2 + (bl0 + tok) * 256 + c2) = s1;
        }
        __syncthreads();
        // KT / X2T transposed writes (from LDS)
        {
            int l0b = bl0 & 127;
            float v0[8], v1[8];
#pragma unroll
            for (int j = 0; j < 8; ++j) { v0[j] = ks[j][t]; v1[j] = as[j][t]; }
            float* KTp  = ws + OFF_KT  + b * 32768 + t * 128 + l0b;
            float* X2Tp = ws + OFF_X2T + b * 32768 + t * 128 + l0b;
            float4 p0 = {v0[0], v0[1], v0[2], v0[3]};
            float4 p1 = {v0[4], v0[5], v0[6], v0[7]};
            *(float4*)KTp = p0; *(float4*)(KTp + 4) = p1;
            float4 r0 = {v1[0], v1[1], v1[2], v1[3]};
            float4 r1 = {v1[4], v1[5], v1[6], v1[7]};
            *(float4*)X2Tp = r0; *(float4*)(X2Tp + 4) = r1;
        }
        // stage 1: gZ2 = X2 @ W2t + b2 - V
        {
            const float* W2t = ws + OFF_W2T + b * 65536;
            float4 a0 = {0, 0, 0, 0}, a1 = {0, 0, 0, 0};
            for (int k0 = 0; k0 < 256; k0 += 8) {
                float4 w0[8], w1[8];
#pragma unroll
                for (int kk = 0; kk < 8; ++kk) {
                    w0[kk] = *(const float4*)(W2t + (k0 + kk) * 256 + c);
                    w1[kk] = *(const float4*)(W2t + (k0 + kk) * 256 + c2);
                }
#pragma unroll
                for (int kk = 0; kk < 8; ++kk) {
                    float xv = as[tok][k0 + kk];
                    a0 = fma4(xv, w0[kk], a0);
                    a1 = fma4(xv, w1[kk], a1);
                }
            }
            float4 bb0 = *(const float4*)(b2 + b * 256 + c);
            float4 bb1 = *(const float4*)(b2 + b * 256 + c2);
            float4 v0 = *(const float4*)(ws + OFF_V + (bl0 + tok) * 256 + c);
            float4 v1 = *(const float4*)(ws + OFF_V + (bl0 + tok) * 256 + c2);
            float4 g0 = {a0.x + bb0.x - v0.x, a0.y + bb0.y - v0.y,
                         a0.z + bb0.z - v0.z, a0.w + bb0.w - v0.w};
            float4 g1 = {a1.x + bb1.x - v1.x, a1.y + bb1.y - v1.y,
                         a1.z + bb1.z - v1.z, a1.w + bb1.w - v1.w};
            *(float4*)&gs[tok][c]  = g0;
            *(float4*)&gs[tok][c2] = g1;
            *(float4*)(ws + OFF_GZ2 + (bl0 + tok) * 256 + c)  = g0;
            *(float4*)(ws + OFF_GZ2 + (bl0 + tok) * 256 + c2) = g1;
        }
        __syncthreads();
        // stage 2: gX2 = gZ2 @ W2(native); gZ1 = gX2 * silu'(Z1)
        {
            const float* W2n = W2nat + b * 65536;
            float4 a0 = {0, 0, 0, 0}, a1 = {0, 0, 0, 0};
            for (int k0 = 0; k0 < 256; k0 += 8) {
                float4 w0[8], w1[8];
#pragma unroll
                for (int kk = 0; kk < 8; ++kk) {
                    w0[kk] = *(const float4*)(W2n + (k0 + kk) * 256 + c);
                    w1[kk] = *(const float4*)(W2n + (k0 + kk) * 256 + c2);
                }
#pragma unroll
                for (int kk = 0; kk < 8; ++kk) {
                    float gv = gs[tok][k0 + kk];
                    a0 = fma4(gv, w0[kk], a0);
                    a1 = fma4(gv, w1[kk], a1);
                }
            }
            float4 z0 = *(float4*)&zs[tok][c];
            float4 z1 = *(float4*)&zs[tok][c2];
            float4 g0 = {dsilu_mul(a0.x, z0.x), dsilu_mul(a0.y, z0.y),
                         dsilu_mul(a0.z, z0.z), dsilu_mul(a0.w, z0.w)};
            float4 g1 = {dsilu_mul(a1.x, z1.x), dsilu_mul(a1.y, z1.y),
                         dsilu_mul(a1.z, z1.z), dsilu_mul(a1.w, z1.w)};
            *(float4*)(ws + OFF_GZ1 + (bl0 + tok) * 256 + c)  = g0;
            *(float4*)(ws + OFF_GZ1 + (bl0 + tok) * 256 + c2) = g1;
        }
    } else if (id < 288) {
        // scan + A-row
        int u = id - 32; int b = u >> 7; int l = u & 127;
        float* sm = smem;
        float* sd = smem + 128;
        float* se = smem + 256;
        if (t < 128) {
            sm[t] = ws[OFF_LOGM + b * Ln + t];
            sd[t] = ws[OFF_LOGWD + b * Ln + t];
        }
        __syncthreads();
        for (int off = 1; off < 128; off <<= 1) {
            float am = 0.0f, ad = 0.0f;
            if (t < 128 && t >= off) { am = sm[t - off]; ad = sd[t - off]; }
            __syncthreads();
            if (t < 128) { sm[t] += am; sd[t] += ad; }
            __syncthreads();
        }
        if (l == 0) {
            if (t < 128) {
                float pm = sm[t], pd = sd[t];
                ws[OFF_PM + b * Ln + t] = pm;
                ws[OFF_PD + b * Ln + t] = pd;
                ws[OFF_MOMCUM + b * Ln + t] = expf(pm);
                ws[OFF_WDCUM + b * Ln + t]  = expf(pd);
                se[t] = expf(pm - pd);
            }
            __syncthreads();
            for (int off = 1; off < 128; off <<= 1) {
                float a = 0.0f;
                if (t < 128 && t >= off) a = se[t - off];
                __syncthreads();
                if (t < 128) se[t] += a;
                __syncthreads();
            }
            if (t < 128) ws[OFF_C + b * Ln + t] = expf(sd[t]) * se[t];
        }
        if (t < 128) {
            int m1 = t;
            float a = 0.0f;
            if (m1 <= l) {
                float pdl = sd[l], pmm1 = sm[m1];
                float s = 0.0f;
                for (int m = m1; m <= l; ++m)
                    s += expf((pdl - sd[m]) + (sm[m] - pmm1));
                a = s;
            }
            ws[OFF_A + (b * Ln + l) * Ln + m1] = a;
        }
    } else {
        // U1 = Q@W1T + b1 ; V1 = Q@mW1T + mb1  (16tok x 128col tiles)
        int u = id - 288; int mat = u >> 5; int rem = u & 31;
        int c0 = (rem >> 4) * 128; int bl0 = (rem & 15) * 16;
        int b = bl0 >> 7;
        const float* W    = ws + (mat == 0 ? OFF_W1T : OFF_MW1T) + b * 65536;
        const float* bias = (mat == 0 ? b1 : mb1) + b * 256;
        float* dst = ws + (mat == 0 ? OFF_U1 : OFF_V1) + bl0 * 256;
        gemm_tile_16x128(ws + OFF_Q + bl0 * 256, W, bias, dst, c0, t, smem);
    }
}

// ---------------------------------------------------------------------------
// LAUNCH 3: fin1 = zq1 (64 blk: score1 + P@GZ1 + U1/V1 -> XQ) +
//           lastw (1024) + lastb (2)
// ---------------------------------------------------------------------------
__global__ __launch_bounds__(256) void fin1_kernel(
    const float* __restrict__ W1, const float* __restrict__ mW1,
    const float* __restrict__ W2nat, const float* __restrict__ mW2,
    const float* __restrict__ b1, const float* __restrict__ mb1,
    const float* __restrict__ b2, const float* __restrict__ mb2,
    float* __restrict__ out, float* __restrict__ ws) {
    __shared__ float smem[6400];
    int id = blockIdx.x, t = threadIdx.x;
    if (id < 64) {
        // zq1: block = (b, l-tile of 8, c-tile of 128)
        int b = id >> 5; int rem = id & 31;
        int l0 = (rem >> 1) * 8; int ct = rem & 1;
        int bl0 = b * 128 + l0; int c0 = ct * 128;
        float (*qs)[260] = (float (*)[260])smem;            // Q rows
        float (*ps)[132] = (float (*)[132])(smem + 2080);   // masked P1
        for (int i = t; i < 512; i += 256) {
            int tok = i >> 6, kq = i & 63;
            *(float4*)&qs[tok][kq * 4] =
                *(const float4*)(ws + OFF_Q + (bl0 + tok) * 256 + kq * 4);
        }
        __syncthreads();
        int tok = t >> 5;
        int l = l0 + tok;
        // score1: s[tok][m] = q . k_m  (16-deep KT batches)
        {
            int mq = t & 31, m0 = 4 * mq;
            const float* KT = ws + OFF_KT + b * 32768 + m0;
            float4 s = {0, 0, 0, 0};
            for (int d0 = 0; d0 < 256; d0 += 16) {
                float4 kb[16];
#pragma unroll
                for (int kk = 0; kk < 16; ++kk)
                    kb[kk] = *(const float4*)(KT + (d0 + kk) * 128);
#pragma unroll
                for (int kk = 0; kk < 16; ++kk)
                    s = fma4(qs[tok][d0 + kk], kb[kk], s);
            }
            float4 A4 = *(const float4*)(ws + OFF_A + (b * 128 + l) * 128 + m0);
            float4 L4 = *(const float4*)(ws + OFF_LR + b * 128 + m0);
            float4 pv;
            pv.x = (m0 + 0 <= l) ? A4.x * L4.x * (1.0f + s.x) : 0.0f;
            pv.y = (m0 + 1 <= l) ? A4.y * L4.y * (1.0f + s.y) : 0.0f;
            pv.z = (m0 + 2 <= l) ? A4.z * L4.z * (1.0f + s.z) : 0.0f;
            pv.w = (m0 + 3 <= l) ? A4.w * L4.w * (1.0f + s.w) : 0.0f;
            *(float4*)&ps[tok][m0] = pv;
        }
        __syncthreads();
        // combine1: XQ = silu(P1@GZ1 - cl*V1 + wd*U1)
        {
            int q = t & 31;
            int c = c0 + 4 * q;
            float cl  = ws[OFF_C + b * 128 + l];
            float wdc = ws[OFF_WDCUM + b * 128 + l];
            float4 p = {0, 0, 0, 0};
            const float* G = ws + OFF_GZ1 + b * 32768 + c;
            int mmax = l0 + 8;
            for (int m0 = 0; m0 < mmax; m0 += 8) {
                float4 gb[8];
#pragma unroll
                for (int kk = 0; kk < 8; ++kk)
                    gb[kk] = *(const float4*)(G + (m0 + kk) * 256);
#pragma unroll
                for (int kk = 0; kk < 8; ++kk)
                    p = fma4(ps[tok][m0 + kk], gb[kk], p);
            }
            float4 u4 = *(const float4*)(ws + OFF_U1 + (bl0 + tok) * 256 + c);
            float4 v4 = *(const float4*)(ws + OFF_V1 + (bl0 + tok) * 256 + c);
            float4 o;
            o.x = silu_f(p.x - cl * v4.x + wdc * u4.x);
            o.y = silu_f(p.y - cl * v4.y + wdc * u4.y);
            o.z = silu_f(p.z - cl * v4.z + wdc * u4.z);
            o.w = silu_f(p.w - cl * v4.w + wdc * u4.w);
            *(float4*)(ws + OFF_XQ + (bl0 + tok) * 256 + c) = o;
        }
    } else if (id < 1088) {
        // lastw
        int u = id - 64; int z = u >> 8; int rem = u & 255;
        int b = z >> 1; int fam = z & 1;
        int i0 = (rem >> 4) * 16, j0 = (rem & 15) * 16;
        float* wa = smem;
        float* wm = smem + 128;
        float (*LA)[16] = (float (*)[16])(smem + 256);
        float (*LM)[16] = (float (*)[16])(smem + 256 + 2048);
        float (*R)[16]  = (float (*)[16])(smem + 256 + 4096);
        const float* lr = ws + OFF_LR + b * Ln;
        const float* Pm = ws + OFF_PM + b * Ln;
        const float* Arow = ws + OFF_A + (b * Ln + Ln - 1) * Ln;
        if (t < 128) {
            wa[t] = Arow[t] * lr[t];
            wm[t] = expf(Pm[Ln - 1] - Pm[t]) * lr[t];
        }
        const float* left  = ws + (fam == 0 ? OFF_GZ1 : OFF_GZ2) + b * Ln * 256;
        const float* right = ws + (fam == 0 ? OFF_K   : OFF_X2 ) + b * Ln * 256;
        __syncthreads();
        for (int e = t; e < 2048; e += 256) {
            int m = e >> 4, i = e & 15;
            float lv = left[m * 256 + i0 + i];
            LA[m][i] = wa[m] * lv;
            LM[m][i] = wm[m] * lv;
            R[m][i]  = right[m * 256 + j0 + i];
        }
        __syncthreads();
        int tx = t & 15, ty = t >> 4;
        float accA = 0.0f, accM = 0.0f;
#pragma unroll 4
        for (int m = 0; m < 128; ++m) {
            accA += LA[m][ty] * R[m][tx];
            accM += LM[m][ty] * R[m][tx];
        }
        float c_last  = ws[OFF_C + b * Ln + Ln - 1];
        float wd_last = ws[OFF_WDCUM + b * Ln + Ln - 1];
        float mc_last = ws[OFF_MOMCUM + b * Ln + Ln - 1];
        int i = i0 + ty, j = j0 + tx;
        const float* base1 = (fam == 0 ? W1 : W2nat) + b * 65536;
        const float* basem = (fam == 0 ? mW1 : mW2) + b * 65536;
        float b1v = base1[i * 256 + j], bmv = basem[i * 256 + j];
        int op = (fam == 0 ? OUT_W1P : OUT_W2P) + (b * 256 + i) * 256 + j;
        int om = (fam == 0 ? OUT_MGW1 : OUT_MGW2) + (b * 256 + i) * 256 + j;
        out[op] = accA - c_last * bmv + wd_last * b1v;
        out[om] = accM - mc_last * bmv;
    } else {
        // lastb
        int b = id - 1088;
        float* wa = smem;
        float* wm = smem + 128;
        if (t < 128) {
            wa[t] = ws[OFF_A + (b * Ln + Ln - 1) * Ln + t] * ws[OFF_LR + b * Ln + t];
            wm[t] = expf(ws[OFF_PM + b * Ln + Ln - 1] - ws[OFF_PM + b * Ln + t]) *
                    ws[OFF_LR + b * Ln + t];
        }
        __syncthreads();
        const float* gz1 = ws + OFF_GZ1 + b * Ln * 256;
        const float* gz2 = ws + OFF_GZ2 + b * Ln * 256;
        float sA1 = 0, sM1 = 0, sA2 = 0, sM2 = 0;
#pragma unroll 4
        for (int m = 0; m < 128; ++m) {
            float g1 = gz1[m * 256 + t], g2 = gz2[m * 256 + t];
            sA1 += wa[m] * g1; sM1 += wm[m] * g1;
            sA2 += wa[m] * g2; sM2 += wm[m] * g2;
        }
        float c_last  = ws[OFF_C + b * Ln + Ln - 1];
        float wd_last = ws[OFF_WDCUM + b * Ln + Ln - 1];
        float mc_last = ws[OFF_MOMCUM + b * Ln + Ln - 1];
        out[OUT_B1P + b * 256 + t]  = sA1 - c_last * mb1[b * 256 + t] + wd_last * b1[b * 256 + t];
        out[OUT_MGB1 + b * 256 + t] = sM1 - mc_last * mb1[b * 256 + t];
        out[OUT_B2P + b * 256 + t]  = sA2 - c_last * mb2[b * 256 + t] + wd_last * b2[b * 256 + t];
        out[OUT_MGB2 + b * 256 + t] = sM2 - mc_last * mb2[b * 256 + t];
    }
}

// ---------------------------------------------------------------------------
// LAUNCH 4: fin2 = score2 (32 blk -> P2) + U2/V2 = XQ@{W2T,mW2T}+bias (64 blk)
// ---------------------------------------------------------------------------
__global__ __launch_bounds__(256) void fin2_kernel(
    const float* __restrict__ b2, const float* __restrict__ mb2,
    float* __restrict__ ws) {
    __shared__ float smem[4160];
    int id = blockIdx.x, t = threadIdx.x;
    if (id < 32) {
        int b = id >> 4; int l0 = (id & 15) * 8; int bl0 = b * 128 + l0;
        float (*qs)[260] = (float (*)[260])smem;
        for (int i = t; i < 512; i += 256) {
            int tok = i >> 6, kq = i & 63;
            *(float4*)&qs[tok][kq * 4] =
                *(const float4*)(ws + OFF_XQ + (bl0 + tok) * 256 + kq * 4);
        }
        __syncthreads();
        int tok = t >> 5, mq = t & 31, m0 = 4 * mq;
        int l = l0 + tok;
        const float* X2T = ws + OFF_X2T + b * 32768 + m0;
        float4 s = {0, 0, 0, 0};
        for (int d0 = 0; d0 < 256; d0 += 16) {
            float4 kb[16];
#pragma unroll
            for (int kk = 0; kk < 16; ++kk)
                kb[kk] = *(const float4*)(X2T + (d0 + kk) * 128);
#pragma unroll
            for (int kk = 0; kk < 16; ++kk)
                s = fma4(qs[tok][d0 + kk], kb[kk], s);
        }
        float4 A4 = *(const float4*)(ws + OFF_A + (b * 128 + l) * 128 + m0);
        float4 L4 = *(const float4*)(ws + OFF_LR + b * 128 + m0);
        float4 pv;
        pv.x = (m0 + 0 <= l) ? A4.x * L4.x * (1.0f + s.x) : 0.0f;
        pv.y = (m0 + 1 <= l) ? A4.y * L4.y * (1.0f + s.y) : 0.0f;
        pv.z = (m0 + 2 <= l) ? A4.z * L4.z * (1.0f + s.z) : 0.0f;
        pv.w = (m0 + 3 <= l) ? A4.w * L4.w * (1.0f + s.w) : 0.0f;
        *(float4*)(ws + OFF_P2 + (b * 128 + l) * 128 + m0) = pv;
    } else {
        int u = id - 32; int mat = u >> 5; int rem = u & 31;
        int c0 = (rem >> 4) * 128; int bl0 = (rem & 15) * 16;
        int b = bl0 >> 7;
        const float* W    = ws + (mat == 0 ? OFF_W2T : OFF_MW2T) + b * 65536;
        const float* bias = (mat == 0 ? b2 : mb2) + b * 256;
        float* dst = ws + (mat == 0 ? OFF_U2 : OFF_V2) + bl0 * 256;
        gemm_tile_16x128(ws + OFF_XQ + bl0 * 256, W, bias, dst, c0, t, smem);
    }
}

// ---------------------------------------------------------------------------
// LAUNCH 5: fin3 = combine2 (64 blk): out = P2@GZ2 - cl*V2 + wd*U2
// ---------------------------------------------------------------------------
__global__ __launch_bounds__(256) void fin3_kernel(
    float* __restrict__ out, float* __restrict__ ws) {
    __shared__ float smem[1056];
    int id = blockIdx.x, t = threadIdx.x;
    int b = id >> 5; int rem = id & 31;
    int l0 = (rem >> 1) * 8; int ct = rem & 1;
    int bl0 = b * 128 + l0; int c0 = ct * 128;
    float (*ps)[132] = (float (*)[132])smem;
    {
        int tok = t >> 5, mq = t & 31;
        *(float4*)&ps[tok][mq * 4] =
            *(const float4*)(ws + OFF_P2 + (b * 128 + l0 + tok) * 128 + mq * 4);
    }
    __syncthreads();
    int tok = t >> 5, q = t & 31;
    int l = l0 + tok;
    int c = c0 + 4 * q;
    float cl  = ws[OFF_C + b * 128 + l];
    float wdc = ws[OFF_WDCUM + b * 128 + l];
    float4 p = {0, 0, 0, 0};
    const float* G = ws + OFF_GZ2 + b * 32768 + c;
    int mmax = l0 + 8;
    for (int m0 = 0; m0 < mmax; m0 += 8) {
        float4 gb[8];
#pragma unroll
        for (int kk = 0; kk < 8; ++kk)
            gb[kk] = *(const float4*)(G + (m0 + kk) * 256);
#pragma unroll
        for (int kk = 0; kk < 8; ++kk)
            p = fma4(ps[tok][m0 + kk], gb[kk], p);
    }
    float4 u4 = *(const float4*)(ws + OFF_U2 + (bl0 + tok) * 256 + c);
    float4 v4 = *(const float4*)(ws + OFF_V2 + (bl0 + tok) * 256 + c);
    float4 o;
    o.x = p.x - cl * v4.x + wdc * u4.x;
    o.y = p.y - cl * v4.y + wdc * u4.y;
    o.z = p.z - cl * v4.z + wdc * u4.z;
    o.w = p.w - cl * v4.w + wdc * u4.w;
    *(float4*)(out + OUT_ZQ2 + (bl0 + tok) * 256 + c) = o;
}

// ---------------------------------------------------------------------------
extern "C" void kernel_launch(void* const* d_in, const int* in_sizes, int n_in,
                              void* d_out, int out_size, void* d_ws, size_t ws_size,
                              hipStream_t stream) {
    const float* x   = (const float*)d_in[0];
    const float* Wq  = (const float*)d_in[1];
    const float* bq  = (const float*)d_in[2];
    const float* Wk  = (const float*)d_in[3];
    const float* bk  = (const float*)d_in[4];
    const float* Wv  = (const float*)d_in[5];
    const float* bv  = (const float*)d_in[6];
    const float* Wlr = (const float*)d_in[7];
    const float* blr = (const float*)d_in[8];
    const float* Wm  = (const float*)d_in[9];
    const float* bm  = (const float*)d_in[10];
    const float* Wd  = (const float*)d_in[11];
    const float* bd  = (const float*)d_in[12];
    const float* W1  = (const float*)d_in[13];
    const float* b1  = (const float*)d_in[14];
    const float* W2  = (const float*)d_in[15];
    const float* b2  = (const float*)d_in[16];
    const float* mW1 = (const float*)d_in[17];
    const float* mb1 = (const float*)d_in[18];
    const float* mW2 = (const float*)d_in[19];
    const float* mb2 = (const float*)d_in[20];
    float* ws  = (float*)d_ws;
    float* out = (float*)d_out;

    prep_kernel<<<672, 256, 0, stream>>>(x, Wq, bq, Wk, bk, Wv, bv,
                                         Wlr, blr, Wm, bm, Wd, bd,
                                         W1, W2, mW1, mW2, ws);
    mid_kernel<<<352, 256, 0, stream>>>(W2, b1, b2, mb1, ws);
    fin1_kernel<<<1090, 256, 0, stream>>>(W1, mW1, W2, mW2,
                                          b1, mb1, b2, mb2, out, ws);
    fin2_kernel<<<96, 256, 0, stream>>>(b2, mb2, ws);
    fin3_kernel<<<64, 256, 0, stream>>>(out, ws);
}